// Round 1
// 286.023 us; speedup vs baseline: 3.2163x; 3.2163x over previous
//
#include <hip/hip_runtime.h>

// CausalSelfAttention  B=2, T=2048, C=768, H=12, hs=64 — MFMA rewrite.
// All three stages (QKV GEMM, flash attention, proj GEMM) now run on
// v_mfma_f32_16x16x32_bf16. Weights are pre-transposed to [N][K] bf16 so
// both GEMM operands read K-contiguous b128 fragments from LDS.
// Runtime dtype detection (bf16 vs fp32 inputs) retained from prior round.

#define BB 2
#define TT 2048
#define CC 768
#define C3 2304
#define HH 12
#define DD 64
#define MM 4096   // B*T

typedef unsigned short u16;
typedef unsigned int u32;
typedef __attribute__((ext_vector_type(8))) u16 u16x8;
typedef __attribute__((ext_vector_type(8))) __bf16 bf16x8;
typedef __attribute__((ext_vector_type(4))) float f32x4;

__device__ __forceinline__ float u2f(u16 u) {
    union { u32 i; float f; } c; c.i = ((u32)u) << 16; return c.f;
}
__device__ __forceinline__ u16 f2u(float f) {
    union { float f; u32 i; } c; c.f = f;
    u32 x = c.i;
    return (u16)((x + 0x7FFFu + ((x >> 16) & 1u)) >> 16);  // RNE
}
__device__ __forceinline__ bf16x8 ldsb8(const u16* p) {
    return __builtin_bit_cast(bf16x8, *(const u16x8*)p);
}
__device__ __forceinline__ f32x4 mfma16(bf16x8 a, bf16x8 b, f32x4 c) {
    return __builtin_amdgcn_mfma_f32_16x16x32_bf16(a, b, c, 0, 0, 0);
}

// ---------------------------------------------------------------------------
// Detector: fp32 data reinterpreted as u16 has ~0.4% words with exponent
// 0xFF in the low halves; genuine bf16 N(0,1) data has none. flag=1 -> fp32.
// ---------------------------------------------------------------------------
__global__ void detect_kernel(const u16* __restrict__ x, int nscan,
                              int* __restrict__ flag)
{
    __shared__ int found;
    if (threadIdx.x == 0) found = 0;
    __syncthreads();
    int local = 0;
    for (int i = threadIdx.x; i < nscan; i += 256) {
        if ((x[i] & 0x7F80u) == 0x7F80u) local = 1;
    }
    if (local) atomicOr(&found, 1);
    __syncthreads();
    if (threadIdx.x == 0) *flag = found ? 1 : 0;
}

// ---------------------------------------------------------------------------
// Weight prep: W[K][N] (bf16 or fp32, per flag) -> Wt[N][K] bf16.
// 64x64 LDS-tiled transpose; mode is a uniform runtime branch.
// ---------------------------------------------------------------------------
__global__ __launch_bounds__(256)
void prep_w(const void* __restrict__ Wv, u16* __restrict__ Wt,
            int K, int N, const int* __restrict__ flag)
{
    __shared__ u16 Ts[64][72];
    const int fm = *flag;
    const int t = threadIdx.x;
    const int n0 = blockIdx.x * 64, k0 = blockIdx.y * 64;
    const int r = t >> 2, c0 = (t & 3) << 4;

    if (fm) {
        const float* W = (const float*)Wv + (size_t)(k0 + r) * N + n0 + c0;
        #pragma unroll
        for (int i = 0; i < 16; i += 4) {
            const float4 v = *(const float4*)(W + i);
            Ts[c0 + i + 0][r] = f2u(v.x);
            Ts[c0 + i + 1][r] = f2u(v.y);
            Ts[c0 + i + 2][r] = f2u(v.z);
            Ts[c0 + i + 3][r] = f2u(v.w);
        }
    } else {
        const u16* W = (const u16*)Wv + (size_t)(k0 + r) * N + n0 + c0;
        const u16x8 a = *(const u16x8*)W;
        const u16x8 c = *(const u16x8*)(W + 8);
        #pragma unroll
        for (int i = 0; i < 8; ++i) { Ts[c0 + i][r] = a[i]; Ts[c0 + 8 + i][r] = c[i]; }
    }
    __syncthreads();
    u16* o = Wt + (size_t)(n0 + r) * K + k0 + c0;
    *(u16x8*)o = *(const u16x8*)&Ts[r][c0];
    *(u16x8*)(o + 8) = *(const u16x8*)&Ts[r][c0 + 8];
}

__global__ void prep_bias(const void* __restrict__ ba, const void* __restrict__ bp,
                          u16* __restrict__ bao, u16* __restrict__ bpo,
                          const int* __restrict__ flag)
{
    const int fm = *flag;
    const int i = blockIdx.x * 256 + threadIdx.x;
    if (i < C3) bao[i] = fm ? f2u(((const float*)ba)[i]) : ((const u16*)ba)[i];
    if (i < CC) bpo[i] = fm ? f2u(((const float*)bp)[i]) : ((const u16*)bp)[i];
}

// ---------------------------------------------------------------------------
// MFMA GEMM: out[M][N] = A[M][K] @ Wt[N][K]^T + bias.
// A: bf16 (AM=0) or fp32 (AM=1). Wt/bias: bf16. out: bf16 (om=0) or f32 (om=1).
// 128x128 tile, BK=32, 256 thr = 4 waves (2x2), 4x4 frags of 16x16x32.
// Reg-staged with next-tile loads issued before compute.
// ---------------------------------------------------------------------------
template <int AM>
__global__ __launch_bounds__(256)
void gemm_mfma(const void* __restrict__ Av, const u16* __restrict__ Bt,
               const u16* __restrict__ bias, void* __restrict__ outv,
               int M, int N, int K, const int* __restrict__ flag,
               int expect, int om)
{
    if (*flag != expect) return;

    __shared__ u16 As[128][40];   // [m][k], row stride 80B (16B-aligned, 2-way banks)
    __shared__ u16 Bs[128][40];   // [n][k]

    const int t = threadIdx.x;
    const int lane = t & 63, wave = t >> 6;
    const int wm = wave >> 1, wn = wave & 1;
    const int l15 = lane & 15, h4 = lane >> 4;
    const int m0 = blockIdx.y * 128, n0 = blockIdx.x * 128;

    const int sr = t >> 1;          // staging row 0..127
    const int sk = (t & 1) << 4;    // 0 or 16

    f32x4 acc[4][4];
    #pragma unroll
    for (int i = 0; i < 4; ++i)
        #pragma unroll
        for (int j = 0; j < 4; ++j) acc[i][j] = (f32x4){0.f, 0.f, 0.f, 0.f};

    u16x8 a0, a1, b0, b1;
    // prologue: load K-tile 0 into regs
    {
        if constexpr (AM == 0) {
            const u16* A = (const u16*)Av + (size_t)(m0 + sr) * K + sk;
            a0 = *(const u16x8*)A; a1 = *(const u16x8*)(A + 8);
        } else {
            const float* A = (const float*)Av + (size_t)(m0 + sr) * K + sk;
            const float4 f0 = *(const float4*)A;
            const float4 f1 = *(const float4*)(A + 4);
            const float4 f2 = *(const float4*)(A + 8);
            const float4 f3 = *(const float4*)(A + 12);
            a0 = (u16x8){f2u(f0.x), f2u(f0.y), f2u(f0.z), f2u(f0.w),
                         f2u(f1.x), f2u(f1.y), f2u(f1.z), f2u(f1.w)};
            a1 = (u16x8){f2u(f2.x), f2u(f2.y), f2u(f2.z), f2u(f2.w),
                         f2u(f3.x), f2u(f3.y), f2u(f3.z), f2u(f3.w)};
        }
        const u16* Bp = Bt + (size_t)(n0 + sr) * K + sk;
        b0 = *(const u16x8*)Bp; b1 = *(const u16x8*)(Bp + 8);
    }

    const int NT = K >> 5;
    for (int kt = 0; kt < NT; ++kt) {
        __syncthreads();                       // prev compute done reading LDS
        *(u16x8*)&As[sr][sk] = a0; *(u16x8*)&As[sr][sk + 8] = a1;
        *(u16x8*)&Bs[sr][sk] = b0; *(u16x8*)&Bs[sr][sk + 8] = b1;
        __syncthreads();                       // staging visible

        if (kt + 1 < NT) {                     // issue next-tile loads early
            const int k0 = (kt + 1) << 5;
            if constexpr (AM == 0) {
                const u16* A = (const u16*)Av + (size_t)(m0 + sr) * K + k0 + sk;
                a0 = *(const u16x8*)A; a1 = *(const u16x8*)(A + 8);
            } else {
                const float* A = (const float*)Av + (size_t)(m0 + sr) * K + k0 + sk;
                const float4 f0 = *(const float4*)A;
                const float4 f1 = *(const float4*)(A + 4);
                const float4 f2 = *(const float4*)(A + 8);
                const float4 f3 = *(const float4*)(A + 12);
                a0 = (u16x8){f2u(f0.x), f2u(f0.y), f2u(f0.z), f2u(f0.w),
                             f2u(f1.x), f2u(f1.y), f2u(f1.z), f2u(f1.w)};
                a1 = (u16x8){f2u(f2.x), f2u(f2.y), f2u(f2.z), f2u(f2.w),
                             f2u(f3.x), f2u(f3.y), f2u(f3.z), f2u(f3.w)};
            }
            const u16* Bp = Bt + (size_t)(n0 + sr) * K + k0 + sk;
            b0 = *(const u16x8*)Bp; b1 = *(const u16x8*)(Bp + 8);
        }

        bf16x8 af[4], bfr[4];
        #pragma unroll
        for (int f = 0; f < 4; ++f) {
            af[f]  = ldsb8(&As[wm * 64 + f * 16 + l15][h4 * 8]);
            bfr[f] = ldsb8(&Bs[wn * 64 + f * 16 + l15][h4 * 8]);
        }
        #pragma unroll
        for (int i = 0; i < 4; ++i)
            #pragma unroll
            for (int j = 0; j < 4; ++j)
                acc[i][j] = mfma16(af[i], bfr[j], acc[i][j]);
    }

    // epilogue: C/D layout col=lane&15, row=(lane>>4)*4+reg
    const int orow = m0 + wm * 64 + h4 * 4;
    const int ocol = n0 + wn * 64 + l15;
    if (om == 0) {
        u16* out = (u16*)outv;
        #pragma unroll
        for (int i = 0; i < 4; ++i)
            #pragma unroll
            for (int j = 0; j < 4; ++j) {
                const int col = ocol + j * 16;
                const float bv = u2f(bias[col]);
                #pragma unroll
                for (int r2 = 0; r2 < 4; ++r2)
                    out[(size_t)(orow + i * 16 + r2) * N + col] = f2u(acc[i][j][r2] + bv);
            }
    } else {
        float* out = (float*)outv;
        #pragma unroll
        for (int i = 0; i < 4; ++i)
            #pragma unroll
            for (int j = 0; j < 4; ++j) {
                const int col = ocol + j * 16;
                const float bv = u2f(bias[col]);
                #pragma unroll
                for (int r2 = 0; r2 < 4; ++r2)
                    out[(size_t)(orow + i * 16 + r2) * N + col] = acc[i][j][r2] + bv;
            }
    }
}

// ---------------------------------------------------------------------------
// MFMA flash attention. qkv bf16 [B,T,3C]; yatt bf16 [B,T,C] (head transpose
// fused into store). Block = 64 q-rows x (h,b); 4 waves x 16 q-rows; KB=64.
// QK^T: A=Q[q][d], B=K[k][d] — both natural, K-contiguous frags.
// PV:   A=P from Ps[q][k]; B=V from Vt[d][k] (transposed staging, XOR-swizzled
//       k-blocks so the scalar transpose writes are ~2-way, not 8-way).
// O-frags share the S-frag q-layout -> online-softmax rescale fully in-reg.
// ---------------------------------------------------------------------------
__global__ __launch_bounds__(256)
void attn_mfma(const u16* __restrict__ qkv, u16* __restrict__ yatt)
{
    __shared__ u16 Qs[64][72];   // [q][d]
    __shared__ u16 Ks[64][72];   // [k][d]
    __shared__ u16 Vt[64][72];   // [d][swz(k)]
    __shared__ u16 Ps[64][72];   // [q][k] (per-wave private 16-row bands)

    const int t = threadIdx.x;
    const int lane = t & 63, w = t >> 6;
    const int l15 = lane & 15, h4 = lane >> 4;
    const int qt = blockIdx.x, h = blockIdx.y, b = blockIdx.z;
    const int q0 = qt * 64;

    const int sr = t >> 2;            // staging row 0..63
    const int sd = (t & 3) << 4;      // 0,16,32,48

    // ---- stage Q tile ----
    {
        const u16* qp = qkv + ((size_t)(b * TT + q0 + sr)) * C3 + h * DD + sd;
        *(u16x8*)&Qs[sr][sd]     = *(const u16x8*)qp;
        *(u16x8*)&Qs[sr][sd + 8] = *(const u16x8*)(qp + 8);
    }

    float m_i[4], l_i[4];
    f32x4 O[4];
    #pragma unroll
    for (int r2 = 0; r2 < 4; ++r2) { m_i[r2] = -1e30f; l_i[r2] = 0.f; }
    #pragma unroll
    for (int d = 0; d < 4; ++d) O[d] = (f32x4){0.f, 0.f, 0.f, 0.f};

    const u16* kb = qkv + ((size_t)(b * TT + sr)) * C3 + CC + h * DD + sd;
    // swizzled V column: element V[k][d] stored at Vt[d][((k>>3)^(d>>4))*8 + (k&7)]
    const int vcol = (((sr >> 3) ^ (t & 3)) << 3) | (sr & 7);

    u16x8 k0r = *(const u16x8*)kb;
    u16x8 k1r = *(const u16x8*)(kb + 8);
    u16x8 v0r = *(const u16x8*)(kb + CC);
    u16x8 v1r = *(const u16x8*)(kb + CC + 8);

    const int NT = qt + 1;
    for (int kt = 0; kt < NT; ++kt) {
        __syncthreads();                       // prev tile's compute done
        *(u16x8*)&Ks[sr][sd]     = k0r;
        *(u16x8*)&Ks[sr][sd + 8] = k1r;
        #pragma unroll
        for (int i = 0; i < 8; ++i) Vt[sd + i][vcol] = v0r[i];
        #pragma unroll
        for (int i = 0; i < 8; ++i) Vt[sd + 8 + i][vcol] = v1r[i];
        __syncthreads();                       // staging visible

        if (kt + 1 < NT) {                     // next-tile loads before compute
            const u16* kp = kb + (size_t)(kt + 1) * 64 * C3;
            k0r = *(const u16x8*)kp;
            k1r = *(const u16x8*)(kp + 8);
            v0r = *(const u16x8*)(kp + CC);
            v1r = *(const u16x8*)(kp + CC + 8);
        }

        // ---- S = Q K^T (scaled after) ----
        const bf16x8 aq0 = ldsb8(&Qs[w * 16 + l15][h4 * 8]);
        const bf16x8 aq1 = ldsb8(&Qs[w * 16 + l15][32 + h4 * 8]);
        f32x4 s[4];
        #pragma unroll
        for (int kf = 0; kf < 4; ++kf) {
            f32x4 z = (f32x4){0.f, 0.f, 0.f, 0.f};
            z = mfma16(aq0, ldsb8(&Ks[kf * 16 + l15][h4 * 8]), z);
            z = mfma16(aq1, ldsb8(&Ks[kf * 16 + l15][32 + h4 * 8]), z);
            s[kf] = z;
        }
        #pragma unroll
        for (int kf = 0; kf < 4; ++kf)
            #pragma unroll
            for (int r2 = 0; r2 < 4; ++r2) s[kf][r2] *= 0.125f;

        // causal mask: only the diagonal tile needs it
        if (kt == qt) {
            #pragma unroll
            for (int kf = 0; kf < 4; ++kf) {
                const int kg = q0 + kf * 16 + l15;
                #pragma unroll
                for (int r2 = 0; r2 < 4; ++r2) {
                    const int qg = q0 + w * 16 + h4 * 4 + r2;
                    if (kg > qg) s[kf][r2] = -1e30f;
                }
            }
        }

        // ---- online softmax (row = q lives on 16 lanes sharing h4) ----
        float alpha[4];
        #pragma unroll
        for (int r2 = 0; r2 < 4; ++r2) {
            float mx = fmaxf(fmaxf(s[0][r2], s[1][r2]), fmaxf(s[2][r2], s[3][r2]));
            mx = fmaxf(mx, __shfl_xor(mx, 1));
            mx = fmaxf(mx, __shfl_xor(mx, 2));
            mx = fmaxf(mx, __shfl_xor(mx, 4));
            mx = fmaxf(mx, __shfl_xor(mx, 8));
            const float mnew = fmaxf(m_i[r2], mx);
            const float a = __expf(m_i[r2] - mnew);
            float rs = 0.f;
            #pragma unroll
            for (int kf = 0; kf < 4; ++kf) {
                const float p = __expf(s[kf][r2] - mnew);
                Ps[w * 16 + h4 * 4 + r2][kf * 16 + l15] = f2u(p);
                rs += p;
            }
            rs += __shfl_xor(rs, 1);
            rs += __shfl_xor(rs, 2);
            rs += __shfl_xor(rs, 4);
            rs += __shfl_xor(rs, 8);
            l_i[r2] = l_i[r2] * a + rs;
            m_i[r2] = mnew;
            alpha[r2] = a;
        }
        #pragma unroll
        for (int d = 0; d < 4; ++d)
            #pragma unroll
            for (int r2 = 0; r2 < 4; ++r2) O[d][r2] *= alpha[r2];

        // ---- O += P V  (Ps rows are wave-private; DS ops in-order per wave) ----
        const bf16x8 ap0 = ldsb8(&Ps[w * 16 + l15][h4 * 8]);
        const bf16x8 ap1 = ldsb8(&Ps[w * 16 + l15][32 + h4 * 8]);
        #pragma unroll
        for (int d = 0; d < 4; ++d) {
            O[d] = mfma16(ap0, ldsb8(&Vt[d * 16 + l15][(h4 ^ d) << 3]), O[d]);
            O[d] = mfma16(ap1, ldsb8(&Vt[d * 16 + l15][((4 + h4) ^ d) << 3]), O[d]);
        }
    }

    // ---- epilogue: normalize, store bf16 [B,T,C] ----
    float inv[4];
    #pragma unroll
    for (int r2 = 0; r2 < 4; ++r2) inv[r2] = 1.0f / l_i[r2];
    u16* yp = yatt + ((size_t)(b * TT + q0 + w * 16 + h4 * 4)) * CC + h * DD + l15;
    #pragma unroll
    for (int r2 = 0; r2 < 4; ++r2)
        #pragma unroll
        for (int d = 0; d < 4; ++d)
            yp[(size_t)r2 * CC + d * 16] = f2u(O[d][r2] * inv[r2]);
}

// ---------------------------------------------------------------------------
extern "C" void kernel_launch(void* const* d_in, const int* in_sizes, int n_in,
                              void* d_out, int out_size, void* d_ws, size_t ws_size,
                              hipStream_t stream)
{
    (void)n_in; (void)out_size; (void)ws_size;

    const void* x      = d_in[0];
    const void* W_attn = d_in[1];
    const void* b_attn = d_in[2];
    const void* W_proj = d_in[3];
    const void* b_proj = d_in[4];

    // workspace layout (~29.9 MB)
    u16* qkv  = (u16*)d_ws;                       // [4096,2304] bf16
    u16* yatt = qkv + (size_t)MM * C3;            // [4096,768]  bf16
    u16* WaT  = yatt + (size_t)MM * CC;           // [2304,768]  bf16 (W_attn^T)
    u16* WpT  = WaT + (size_t)C3 * CC;            // [768,768]   bf16 (W_proj^T)
    u16* ba   = WpT + (size_t)CC * CC;            // [2304] bf16
    u16* bp   = ba + C3;                          // [768]  bf16
    int* flag = (int*)(bp + CC);

    int nscan = in_sizes[0] < 65536 ? in_sizes[0] : 65536;
    detect_kernel<<<1, 256, 0, stream>>>((const u16*)x, nscan, flag);

    // prep: transpose weights to [N][K] bf16, convert biases (runtime mode)
    prep_bias<<<9, 256, 0, stream>>>(b_attn, b_proj, ba, bp, flag);
    prep_w<<<dim3(C3 / 64, CC / 64), 256, 0, stream>>>(W_attn, WaT, CC, C3, flag);
    prep_w<<<dim3(CC / 64, CC / 64), 256, 0, stream>>>(W_proj, WpT, CC, CC, flag);

    // 1) qkv = x @ W_attn + b_attn (bf16 out) — A-mode self-selects via flag
    gemm_mfma<0><<<dim3(C3 / 128, MM / 128), 256, 0, stream>>>(
        x, WaT, ba, (void*)qkv, MM, C3, CC, flag, 0, 0);
    gemm_mfma<1><<<dim3(C3 / 128, MM / 128), 256, 0, stream>>>(
        x, WaT, ba, (void*)qkv, MM, C3, CC, flag, 1, 0);

    // 2) causal flash attention (mode-independent)
    attn_mfma<<<dim3(TT / 64, HH, BB), 256, 0, stream>>>(qkv, yatt);

    // 3) out = yatt @ W_proj + b_proj — A always bf16; out dtype per mode
    gemm_mfma<0><<<dim3(CC / 128, MM / 128), 256, 0, stream>>>(
        yatt, WpT, bp, d_out, MM, CC, CC, flag, 0, 0);
    gemm_mfma<0><<<dim3(CC / 128, MM / 128), 256, 0, stream>>>(
        yatt, WpT, bp, d_out, MM, CC, CC, flag, 1, 1);
}

// Round 2
// 241.161 us; speedup vs baseline: 3.8146x; 1.1860x over previous
//
#include <hip/hip_runtime.h>

// CausalSelfAttention  B=2, T=2048, C=768, H=12, hs=64 — round 2.
// Changes vs round 1:
//  * attn: LPT-balanced work table (host-computed, memcpyAsync'd). Blocks
//    {c, c+256, c+512} share a CU; the table gives each CU a qt-triple
//    summing to ~49.5 tiles (was: same qt 3x -> worst CU 96 tiles).
//  * attn: 1/8 softmax scale folded into Q staging (exact, pow2).
//  * gemm: global_load_lds width-16 staging with pre-swizzled source
//    (linear LDS dest, XOR chunk swizzle -> 2-way-free b128 frag reads).
//  * prep_x materializes x as bf16 (into the yatt slot; disjoint lifetime),
//    so every GEMM launches exactly once (out dtype follows the flag).

#define BB 2
#define TT 2048
#define CC 768
#define C3 2304
#define HH 12
#define DD 64
#define MM 4096   // B*T

typedef unsigned short u16;
typedef unsigned int u32;
typedef __attribute__((ext_vector_type(8))) u16 u16x8;
typedef __attribute__((ext_vector_type(8))) __bf16 bf16x8;
typedef __attribute__((ext_vector_type(4))) float f32x4;

__device__ __forceinline__ float u2f(u16 u) {
    union { u32 i; float f; } c; c.i = ((u32)u) << 16; return c.f;
}
__device__ __forceinline__ u16 f2u(float f) {
    union { float f; u32 i; } c; c.f = f;
    u32 x = c.i;
    return (u16)((x + 0x7FFFu + ((x >> 16) & 1u)) >> 16);  // RNE
}
__device__ __forceinline__ bf16x8 ldsb8(const u16* p) {
    return __builtin_bit_cast(bf16x8, *(const u16x8*)p);
}
__device__ __forceinline__ f32x4 mfma16(bf16x8 a, bf16x8 b, f32x4 c) {
    return __builtin_amdgcn_mfma_f32_16x16x32_bf16(a, b, c, 0, 0, 0);
}
typedef __attribute__((address_space(1))) const u32 gu32;
typedef __attribute__((address_space(3))) u32 lu32;
__device__ __forceinline__ void gload16(const u16* gp, u16* lp) {
    __builtin_amdgcn_global_load_lds((gu32*)(const void*)gp, (lu32*)(void*)lp,
                                     16, 0, 0);
}

// ---------------------------------------------------------------------------
// Detector: fp32 data reinterpreted as u16 has ~0.4% words with exponent
// 0xFF in the low halves; genuine bf16 N(0,1) data has none. flag=1 -> fp32.
// ---------------------------------------------------------------------------
__global__ void detect_kernel(const u16* __restrict__ x, int nscan,
                              int* __restrict__ flag)
{
    __shared__ int found;
    if (threadIdx.x == 0) found = 0;
    __syncthreads();
    int local = 0;
    for (int i = threadIdx.x; i < nscan; i += 256) {
        if ((x[i] & 0x7F80u) == 0x7F80u) local = 1;
    }
    if (local) atomicOr(&found, 1);
    __syncthreads();
    if (threadIdx.x == 0) *flag = found ? 1 : 0;
}

// ---------------------------------------------------------------------------
// Weight prep: W[K][N] (bf16 or fp32, per flag) -> Wt[N][K] bf16.
// ---------------------------------------------------------------------------
__global__ __launch_bounds__(256)
void prep_w(const void* __restrict__ Wv, u16* __restrict__ Wt,
            int K, int N, const int* __restrict__ flag)
{
    __shared__ u16 Ts[64][72];
    const int fm = *flag;
    const int t = threadIdx.x;
    const int n0 = blockIdx.x * 64, k0 = blockIdx.y * 64;
    const int r = t >> 2, c0 = (t & 3) << 4;

    if (fm) {
        const float* W = (const float*)Wv + (size_t)(k0 + r) * N + n0 + c0;
        #pragma unroll
        for (int i = 0; i < 16; i += 4) {
            const float4 v = *(const float4*)(W + i);
            Ts[c0 + i + 0][r] = f2u(v.x);
            Ts[c0 + i + 1][r] = f2u(v.y);
            Ts[c0 + i + 2][r] = f2u(v.z);
            Ts[c0 + i + 3][r] = f2u(v.w);
        }
    } else {
        const u16* W = (const u16*)Wv + (size_t)(k0 + r) * N + n0 + c0;
        const u16x8 a = *(const u16x8*)W;
        const u16x8 c = *(const u16x8*)(W + 8);
        #pragma unroll
        for (int i = 0; i < 8; ++i) { Ts[c0 + i][r] = a[i]; Ts[c0 + 8 + i][r] = c[i]; }
    }
    __syncthreads();
    u16* o = Wt + (size_t)(n0 + r) * K + k0 + c0;
    *(u16x8*)o = *(const u16x8*)&Ts[r][c0];
    *(u16x8*)(o + 8) = *(const u16x8*)&Ts[r][c0 + 8];
}

__global__ void prep_bias(const void* __restrict__ ba, const void* __restrict__ bp,
                          u16* __restrict__ bao, u16* __restrict__ bpo,
                          const int* __restrict__ flag)
{
    const int fm = *flag;
    const int i = blockIdx.x * 256 + threadIdx.x;
    if (i < C3) bao[i] = fm ? f2u(((const float*)ba)[i]) : ((const u16*)ba)[i];
    if (i < CC) bpo[i] = fm ? f2u(((const float*)bp)[i]) : ((const u16*)bp)[i];
}

// x -> bf16 workspace copy (so the GEMM has a single bf16 A-path).
__global__ __launch_bounds__(256)
void prep_x(const void* __restrict__ xv, u16* __restrict__ xb,
            const int* __restrict__ flag)
{
    const int fm = *flag;
    const size_t i = (size_t)blockIdx.x * 256 + threadIdx.x;   // octet index
    if (fm) {
        const float* x = (const float*)xv + i * 8;
        u16x8 o;
        #pragma unroll
        for (int j = 0; j < 8; ++j) o[j] = f2u(x[j]);
        *(u16x8*)(xb + i * 8) = o;
    } else {
        *(u16x8*)(xb + i * 8) = *(const u16x8*)((const u16*)xv + i * 8);
    }
}

// ---------------------------------------------------------------------------
// MFMA GEMM: out[M][N] = A[M][K] @ Bt[N][K]^T + bias.  A/Bt/bias bf16.
// 128x128 tile, BK=32, 4 waves, 4x4 frags of 16x16x32.
// Staging via global_load_lds(16B): LDS dest is linear (lane order); the
// SOURCE address is pre-swizzled so LDS chunk c' = c ^ swz. Frag reads apply
// the same swizzle -> 16-lane b128 reads cover all 32 banks (2-way, free).
//   write side: lane -> (r = base+lane/4, c = (lane&3) ^ (lane>>4))
//   read  side: (r, chunk h4) lives at c' = h4 ^ ((l15>>2)&3)
// out dtype: om_sel ? (*flag ? f32 : bf16) : bf16.
// ---------------------------------------------------------------------------
__global__ __launch_bounds__(256)
void gemm_mfma(const u16* __restrict__ A, const u16* __restrict__ Bt,
               const u16* __restrict__ bias, void* __restrict__ outv,
               int M, int N, int K, const int* __restrict__ flag, int om_sel)
{
    __shared__ u16 As[128 * 32];
    __shared__ u16 Bs[128 * 32];

    const int t = threadIdx.x;
    const int lane = t & 63, wave = t >> 6;
    const int wm = wave >> 1, wn = wave & 1;
    const int l15 = lane & 15, h4 = lane >> 4;
    const int m0 = blockIdx.y * 128, n0 = blockIdx.x * 128;
    const int om = om_sel ? *flag : 0;

    // staging geometry: instruction j of this wave writes LDS 16B-slots
    // [(wave*2+j)*64 + lane]; slot s -> row s>>2, chunk' s&3.
    const int r0 = wave * 32 + (lane >> 2);       // j=0 row
    const int r1 = r0 + 16;                       // j=1 row
    const int cs = ((lane & 3) ^ (lane >> 4)) * 8;  // swizzled source chunk (u16)
    const u16* Abase = A + (size_t)(m0 + r0) * K + cs;
    const u16* Abas1 = A + (size_t)(m0 + r1) * K + cs;
    const u16* Bbase = Bt + (size_t)(n0 + r0) * K + cs;
    const u16* Bbas1 = Bt + (size_t)(n0 + r1) * K + cs;
    u16* Ad0 = &As[(wave * 2 + 0) * 512];
    u16* Ad1 = &As[(wave * 2 + 1) * 512];
    u16* Bd0 = &Bs[(wave * 2 + 0) * 512];
    u16* Bd1 = &Bs[(wave * 2 + 1) * 512];

    f32x4 acc[4][4];
    #pragma unroll
    for (int i = 0; i < 4; ++i)
        #pragma unroll
        for (int j = 0; j < 4; ++j) acc[i][j] = (f32x4){0.f, 0.f, 0.f, 0.f};

    // frag read addresses (u16 units): row*32 + (h4 ^ (l15>>2))*8
    const int csr = (h4 ^ (l15 >> 2)) * 8;
    const int arow = wm * 64 + l15;
    const int brow = wn * 64 + l15;

    const int NT = K >> 5;
    for (int kt = 0; kt < NT; ++kt) {
        if (kt) __syncthreads();               // prev compute done with LDS
        const int k0 = kt << 5;
        gload16(Abase + k0, Ad0);
        gload16(Abas1 + k0, Ad1);
        gload16(Bbase + k0, Bd0);
        gload16(Bbas1 + k0, Bd1);
        __syncthreads();                       // drains vmcnt + barrier

        bf16x8 af[4], bfr[4];
        #pragma unroll
        for (int f = 0; f < 4; ++f) {
            af[f]  = ldsb8(&As[(arow + f * 16) * 32 + csr]);
            bfr[f] = ldsb8(&Bs[(brow + f * 16) * 32 + csr]);
        }
        #pragma unroll
        for (int i = 0; i < 4; ++i)
            #pragma unroll
            for (int j = 0; j < 4; ++j)
                acc[i][j] = mfma16(af[i], bfr[j], acc[i][j]);
    }

    // epilogue: C/D layout col=lane&15, row=(lane>>4)*4+reg
    const int orow = m0 + wm * 64 + h4 * 4;
    const int ocol = n0 + wn * 64 + l15;
    if (om == 0) {
        u16* out = (u16*)outv;
        #pragma unroll
        for (int i = 0; i < 4; ++i)
            #pragma unroll
            for (int j = 0; j < 4; ++j) {
                const int col = ocol + j * 16;
                const float bv = u2f(bias[col]);
                #pragma unroll
                for (int r2 = 0; r2 < 4; ++r2)
                    out[(size_t)(orow + i * 16 + r2) * N + col] = f2u(acc[i][j][r2] + bv);
            }
    } else {
        float* out = (float*)outv;
        #pragma unroll
        for (int i = 0; i < 4; ++i)
            #pragma unroll
            for (int j = 0; j < 4; ++j) {
                const int col = ocol + j * 16;
                const float bv = u2f(bias[col]);
                #pragma unroll
                for (int r2 = 0; r2 < 4; ++r2)
                    out[(size_t)(orow + i * 16 + r2) * N + col] = acc[i][j][r2] + bv;
            }
    }
}

// ---------------------------------------------------------------------------
// MFMA flash attention, LPT-scheduled. Work item (qt,h,b) comes from tab[bid]
// so CU-sharing blocks {c, c+256, c+512} carry a balanced qt-triple.
// Inner structure identical to the verified round-1 kernel, except the 1/8
// scale is folded into Q staging (exact pow2 scale in bf16).
// ---------------------------------------------------------------------------
__global__ __launch_bounds__(256)
void attn_mfma(const u16* __restrict__ qkv, u16* __restrict__ yatt,
               const int* __restrict__ tab)
{
    __shared__ u16 Qs[64][72];   // [q][d]  (pre-scaled by 1/8)
    __shared__ u16 Ks[64][72];   // [k][d]
    __shared__ u16 Vt[64][72];   // [d][swz(k)]
    __shared__ u16 Ps[64][72];   // [q][k]

    const int item = tab[blockIdx.x];
    const int qt = item & 255, h = (item >> 8) & 255, b = item >> 16;

    const int t = threadIdx.x;
    const int lane = t & 63, w = t >> 6;
    const int l15 = lane & 15, h4 = lane >> 4;
    const int q0 = qt * 64;

    const int sr = t >> 2;            // staging row 0..63
    const int sd = (t & 3) << 4;      // 0,16,32,48

    // ---- stage Q tile (scaled by 1/8) ----
    {
        const u16* qp = qkv + ((size_t)(b * TT + q0 + sr)) * C3 + h * DD + sd;
        const u16x8 v0 = *(const u16x8*)qp;
        const u16x8 v1 = *(const u16x8*)(qp + 8);
        u16x8 o0, o1;
        #pragma unroll
        for (int i = 0; i < 8; ++i) {
            o0[i] = f2u(u2f(v0[i]) * 0.125f);
            o1[i] = f2u(u2f(v1[i]) * 0.125f);
        }
        *(u16x8*)&Qs[sr][sd]     = o0;
        *(u16x8*)&Qs[sr][sd + 8] = o1;
    }

    float m_i[4], l_i[4];
    f32x4 O[4];
    #pragma unroll
    for (int r2 = 0; r2 < 4; ++r2) { m_i[r2] = -1e30f; l_i[r2] = 0.f; }
    #pragma unroll
    for (int d = 0; d < 4; ++d) O[d] = (f32x4){0.f, 0.f, 0.f, 0.f};

    const u16* kb = qkv + ((size_t)(b * TT + sr)) * C3 + CC + h * DD + sd;
    // swizzled V column: V[k][d] stored at Vt[d][((k>>3)^(d>>4))*8 + (k&7)]
    const int vcol = (((sr >> 3) ^ (t & 3)) << 3) | (sr & 7);

    u16x8 k0r = *(const u16x8*)kb;
    u16x8 k1r = *(const u16x8*)(kb + 8);
    u16x8 v0r = *(const u16x8*)(kb + CC);
    u16x8 v1r = *(const u16x8*)(kb + CC + 8);

    const int NT = qt + 1;
    for (int kt = 0; kt < NT; ++kt) {
        __syncthreads();                       // prev tile's compute done
        *(u16x8*)&Ks[sr][sd]     = k0r;
        *(u16x8*)&Ks[sr][sd + 8] = k1r;
        #pragma unroll
        for (int i = 0; i < 8; ++i) Vt[sd + i][vcol] = v0r[i];
        #pragma unroll
        for (int i = 0; i < 8; ++i) Vt[sd + 8 + i][vcol] = v1r[i];
        __syncthreads();                       // staging visible

        if (kt + 1 < NT) {                     // next-tile loads before compute
            const u16* kp = kb + (size_t)(kt + 1) * 64 * C3;
            k0r = *(const u16x8*)kp;
            k1r = *(const u16x8*)(kp + 8);
            v0r = *(const u16x8*)(kp + CC);
            v1r = *(const u16x8*)(kp + CC + 8);
        }

        // ---- S = (Q/8) K^T ----
        const bf16x8 aq0 = ldsb8(&Qs[w * 16 + l15][h4 * 8]);
        const bf16x8 aq1 = ldsb8(&Qs[w * 16 + l15][32 + h4 * 8]);
        f32x4 s[4];
        #pragma unroll
        for (int kf = 0; kf < 4; ++kf) {
            f32x4 z = (f32x4){0.f, 0.f, 0.f, 0.f};
            z = mfma16(aq0, ldsb8(&Ks[kf * 16 + l15][h4 * 8]), z);
            z = mfma16(aq1, ldsb8(&Ks[kf * 16 + l15][32 + h4 * 8]), z);
            s[kf] = z;
        }

        // causal mask: only the diagonal tile needs it
        if (kt == qt) {
            #pragma unroll
            for (int kf = 0; kf < 4; ++kf) {
                const int kg = q0 + kf * 16 + l15;
                #pragma unroll
                for (int r2 = 0; r2 < 4; ++r2) {
                    const int qg = q0 + w * 16 + h4 * 4 + r2;
                    if (kg > qg) s[kf][r2] = -1e30f;
                }
            }
        }

        // ---- online softmax (row = q lives on 16 lanes sharing h4) ----
        float alpha[4];
        #pragma unroll
        for (int r2 = 0; r2 < 4; ++r2) {
            float mx = fmaxf(fmaxf(s[0][r2], s[1][r2]), fmaxf(s[2][r2], s[3][r2]));
            mx = fmaxf(mx, __shfl_xor(mx, 1));
            mx = fmaxf(mx, __shfl_xor(mx, 2));
            mx = fmaxf(mx, __shfl_xor(mx, 4));
            mx = fmaxf(mx, __shfl_xor(mx, 8));       // 16-lane row group
            const float mnew = fmaxf(m_i[r2], mx);
            const float a = __expf(m_i[r2] - mnew);
            float rs = 0.f;
            #pragma unroll
            for (int kf = 0; kf < 4; ++kf) {
                const float p = __expf(s[kf][r2] - mnew);
                Ps[w * 16 + h4 * 4 + r2][kf * 16 + l15] = f2u(p);
                rs += p;
            }
            rs += __shfl_xor(rs, 1);
            rs += __shfl_xor(rs, 2);
            rs += __shfl_xor(rs, 4);
            rs += __shfl_xor(rs, 8);
            l_i[r2] = l_i[r2] * a + rs;
            m_i[r2] = mnew;
            alpha[r2] = a;
        }
        #pragma unroll
        for (int d = 0; d < 4; ++d)
            #pragma unroll
            for (int r2 = 0; r2 < 4; ++r2) O[d][r2] *= alpha[r2];

        // ---- O += P @ V ----
        const bf16x8 ap0 = ldsb8(&Ps[w * 16 + l15][h4 * 8]);
        const bf16x8 ap1 = ldsb8(&Ps[w * 16 + l15][32 + h4 * 8]);
        #pragma unroll
        for (int d = 0; d < 4; ++d) {
            O[d] = mfma16(ap0, ldsb8(&Vt[d * 16 + l15][(h4 ^ d) << 3]), O[d]);
            O[d] = mfma16(ap1, ldsb8(&Vt[d * 16 + l15][((4 + h4) ^ d) << 3]), O[d]);
        }
    }

    // ---- epilogue: normalize, store bf16 [B,T,C] ----
    float inv[4];
    #pragma unroll
    for (int r2 = 0; r2 < 4; ++r2) inv[r2] = 1.0f / l_i[r2];
    u16* yp = yatt + ((size_t)(b * TT + q0 + w * 16 + h4 * 4)) * CC + h * DD + l15;
    #pragma unroll
    for (int r2 = 0; r2 < 4; ++r2)
        #pragma unroll
        for (int d = 0; d < 4; ++d)
            yp[(size_t)r2 * CC + d * 16] = f2u(O[d][r2] * inv[r2]);
}

// ---------------------------------------------------------------------------
extern "C" void kernel_launch(void* const* d_in, const int* in_sizes, int n_in,
                              void* d_out, int out_size, void* d_ws, size_t ws_size,
                              hipStream_t stream)
{
    (void)n_in; (void)out_size; (void)ws_size;

    const void* x      = d_in[0];
    const void* W_attn = d_in[1];
    const void* b_attn = d_in[2];
    const void* W_proj = d_in[3];
    const void* b_proj = d_in[4];

    // workspace layout (~30 MB)
    u16* qkv  = (u16*)d_ws;                       // [4096,2304] bf16
    u16* yatt = qkv + (size_t)MM * C3;            // [4096,768]  bf16
    u16* xb   = yatt;                             // bf16 x — lifetime disjoint
    u16* WaT  = yatt + (size_t)MM * CC;           // [2304,768]  bf16 (W_attn^T)
    u16* WpT  = WaT + (size_t)C3 * CC;            // [768,768]   bf16 (W_proj^T)
    u16* ba   = WpT + (size_t)CC * CC;            // [2304] bf16
    u16* bp   = ba + C3;                          // [768]  bf16
    int* flag = (int*)(bp + CC);                  // 1 int
    int* dtab = flag + 1;                         // 768 ints (LPT schedule)

    // ---- host-side LPT schedule (once): 768 items (qt,h,b), work=qt+1,
    // into 256 bins of 3; block id = bin + 256*slot so CU-sharing triples
    // {c, c+256, c+512} are load-balanced (sum 49-50 tiles).
    static int host_tab[768];
    static bool tab_init = false;
    if (!tab_init) {
        int loads[256], cnt[256];
        for (int i = 0; i < 256; ++i) { loads[i] = 0; cnt[i] = 0; }
        for (int qt = TT / 64 - 1; qt >= 0; --qt) {
            for (int hb = 0; hb < HH * BB; ++hb) {
                int best = -1;
                for (int bin = 0; bin < 256; ++bin)
                    if (cnt[bin] < 3 && (best < 0 || loads[bin] < loads[best]))
                        best = bin;
                host_tab[best + 256 * cnt[best]] =
                    qt | ((hb % HH) << 8) | ((hb / HH) << 16);
                loads[best] += qt + 1;
                cnt[best]++;
            }
        }
        tab_init = true;
    }
    hipMemcpyAsync(dtab, host_tab, sizeof(host_tab), hipMemcpyHostToDevice, stream);

    int nscan = in_sizes[0] < 65536 ? in_sizes[0] : 65536;
    detect_kernel<<<1, 256, 0, stream>>>((const u16*)x, nscan, flag);

    // prep: biases, transposed weights, bf16 x
    prep_bias<<<9, 256, 0, stream>>>(b_attn, b_proj, ba, bp, flag);
    prep_w<<<dim3(C3 / 64, CC / 64), 256, 0, stream>>>(W_attn, WaT, CC, C3, flag);
    prep_w<<<dim3(CC / 64, CC / 64), 256, 0, stream>>>(W_proj, WpT, CC, CC, flag);
    prep_x<<<MM * CC / 8 / 256, 256, 0, stream>>>(x, xb, flag);

    // 1) qkv = xb @ W_attn + b_attn (bf16 out)
    gemm_mfma<<<dim3(C3 / 128, MM / 128), 256, 0, stream>>>(
        xb, WaT, ba, (void*)qkv, MM, C3, CC, flag, 0);

    // 2) causal flash attention (LPT-scheduled)
    attn_mfma<<<dim3(TT / 64 * HH * BB, 1, 1), 256, 0, stream>>>(qkv, yatt, dtab);

    // 3) out = yatt @ W_proj + b_proj (out dtype follows flag)
    gemm_mfma<<<dim3(CC / 128, MM / 128), 256, 0, stream>>>(
        yatt, WpT, bp, d_out, MM, CC, CC, flag, 1);
}

// Round 3
// 228.311 us; speedup vs baseline: 4.0293x; 1.0563x over previous
//
#include <hip/hip_runtime.h>

// CausalSelfAttention  B=2, T=2048, C=768, H=12, hs=64 — round 3.
// * gemm: double-buffered LDS + counted s_waitcnt vmcnt(4) (T3 2-phase min):
//   next K-tile's global_load_lds fly under current tile's MFMA.
// * attn: V staged as packed-b32 transposed pairs (2-way, conflict-free);
//   P-store column XOR swizzle (4-way -> 2-way); Q frags hoisted; native
//   RNE bf16 casts in the hot path.
// * closed-form balanced schedule (qt triple sums 46/47) replaces the LPT
//   table + memcpy; host-side dtype detection from in_sizes (detector kept
//   as fallback); all prep fused into one kernel. 9 graph nodes -> 4-5.

#define BB 2
#define TT 2048
#define CC 768
#define C3 2304
#define HH 12
#define DD 64
#define MM 4096   // B*T

typedef unsigned short u16;
typedef unsigned int u32;
typedef __attribute__((ext_vector_type(8))) u16 u16x8;
typedef __attribute__((ext_vector_type(8))) __bf16 bf16x8;
typedef __attribute__((ext_vector_type(4))) float f32x4;

__device__ __forceinline__ float u2f(u16 u) {
    union { u32 i; float f; } c; c.i = ((u32)u) << 16; return c.f;
}
__device__ __forceinline__ u16 f2u(float f) {
    union { float f; u32 i; } c; c.f = f;
    u32 x = c.i;
    return (u16)((x + 0x7FFFu + ((x >> 16) & 1u)) >> 16);  // RNE
}
__device__ __forceinline__ u16 f2b(float f) {              // RNE via v_cvt
    __bf16 h = (__bf16)f; return __builtin_bit_cast(u16, h);
}
__device__ __forceinline__ bf16x8 ldsb8(const u16* p) {
    return __builtin_bit_cast(bf16x8, *(const u16x8*)p);
}
__device__ __forceinline__ f32x4 mfma16(bf16x8 a, bf16x8 b, f32x4 c) {
    return __builtin_amdgcn_mfma_f32_16x16x32_bf16(a, b, c, 0, 0, 0);
}
typedef __attribute__((address_space(1))) const u32 gu32;
typedef __attribute__((address_space(3))) u32 lu32;
__device__ __forceinline__ void gload16(const u16* gp, u16* lp) {
    __builtin_amdgcn_global_load_lds((gu32*)(const void*)gp, (lu32*)(void*)lp,
                                     16, 0, 0);
}
__device__ __forceinline__ void barrier_raw() {
    asm volatile("" ::: "memory");
    __builtin_amdgcn_s_barrier();
    asm volatile("" ::: "memory");
}

// ---------------------------------------------------------------------------
// Fallback detector (only launched when host can't infer dtype from sizes):
// fp32 data reinterpreted as u16 has ~0.4% words with exponent 0xFF.
// ---------------------------------------------------------------------------
__global__ void detect_kernel(const u16* __restrict__ x, int nscan,
                              int* __restrict__ flag)
{
    __shared__ int found;
    if (threadIdx.x == 0) found = 0;
    __syncthreads();
    int local = 0;
    for (int i = threadIdx.x; i < nscan; i += 256) {
        if ((x[i] & 0x7F80u) == 0x7F80u) local = 1;
    }
    if (local) atomicOr(&found, 1);
    __syncthreads();
    if (threadIdx.x == 0) *flag = found ? 1 : 0;
}

// ---------------------------------------------------------------------------
// Fused prep: block ranges do {W_attn^T, W_proj^T, x->bf16, biases}.
// ---------------------------------------------------------------------------
__device__ void prep_w_body(const void* __restrict__ Wv, u16* __restrict__ Wt,
                            int K, int N, int bx, int by, int fm,
                            u16 (*Ts)[72])
{
    const int t = threadIdx.x;
    const int n0 = bx * 64, k0 = by * 64;
    const int r = t >> 2, c0 = (t & 3) << 4;

    if (fm) {
        const float* W = (const float*)Wv + (size_t)(k0 + r) * N + n0 + c0;
        #pragma unroll
        for (int i = 0; i < 16; i += 4) {
            const float4 v = *(const float4*)(W + i);
            Ts[c0 + i + 0][r] = f2u(v.x);
            Ts[c0 + i + 1][r] = f2u(v.y);
            Ts[c0 + i + 2][r] = f2u(v.z);
            Ts[c0 + i + 3][r] = f2u(v.w);
        }
    } else {
        const u16* W = (const u16*)Wv + (size_t)(k0 + r) * N + n0 + c0;
        const u16x8 a = *(const u16x8*)W;
        const u16x8 c = *(const u16x8*)(W + 8);
        #pragma unroll
        for (int i = 0; i < 8; ++i) { Ts[c0 + i][r] = a[i]; Ts[c0 + 8 + i][r] = c[i]; }
    }
    __syncthreads();
    u16* o = Wt + (size_t)(n0 + r) * K + k0 + c0;
    *(u16x8*)o = *(const u16x8*)&Ts[r][c0];
    *(u16x8*)(o + 8) = *(const u16x8*)&Ts[r][c0 + 8];
}

__global__ __launch_bounds__(256)
void fused_prep(const void* __restrict__ x, const void* __restrict__ Wa,
                const void* __restrict__ ba, const void* __restrict__ Wp,
                const void* __restrict__ bp,
                u16* __restrict__ xb, u16* __restrict__ WaT,
                u16* __restrict__ WpT, u16* __restrict__ bao,
                u16* __restrict__ bpo,
                const int* __restrict__ flag, int mode)
{
    __shared__ u16 Ts[64][72];
    const int fm = (mode >= 0) ? mode : *flag;
    const int blk = blockIdx.x;
    const int t = threadIdx.x;

    if (blk < 432) {                       // W_attn: grid 36 x 12
        prep_w_body(Wa, WaT, CC, C3, blk % 36, blk / 36, fm, Ts);
    } else if (blk < 576) {                // W_proj: grid 12 x 12
        const int b2 = blk - 432;
        prep_w_body(Wp, WpT, CC, CC, b2 % 12, b2 / 12, fm, Ts);
    } else if (blk < 2112) {               // x -> bf16 (octets)
        const size_t i = (size_t)(blk - 576) * 256 + t;
        if (fm) {
            const float* xp = (const float*)x + i * 8;
            u16x8 o;
            #pragma unroll
            for (int j = 0; j < 8; ++j) o[j] = f2u(xp[j]);
            *(u16x8*)(xb + i * 8) = o;
        } else {
            *(u16x8*)(xb + i * 8) = *(const u16x8*)((const u16*)x + i * 8);
        }
    } else {                               // biases
        const int i = (blk - 2112) * 256 + t;
        if (i < C3) bao[i] = fm ? f2u(((const float*)ba)[i]) : ((const u16*)ba)[i];
        if (i < CC) bpo[i] = fm ? f2u(((const float*)bp)[i]) : ((const u16*)bp)[i];
    }
}

// ---------------------------------------------------------------------------
// MFMA GEMM: out[M][N] = A[M][K] @ Bt[N][K]^T + bias.  A/Bt/bias bf16.
// 128x128 tile, BK=32, 4 waves, 4x4 frags of 16x16x32.
// Double-buffered global_load_lds staging with counted vmcnt (T3 2-phase):
// STAGE(next) -> s_waitcnt vmcnt(4) -> barrier -> MFMA(cur) -> barrier.
// Source-side XOR chunk swizzle (round-2 verified) keeps frag reads 2-way.
// out dtype: om_sel ? (fp32-mode ? f32 : bf16) : bf16.
// ---------------------------------------------------------------------------
__global__ __launch_bounds__(256)
void gemm_mfma(const u16* __restrict__ A, const u16* __restrict__ Bt,
               const u16* __restrict__ bias, void* __restrict__ outv,
               int M, int N, int K, const int* __restrict__ flag,
               int mode, int om_sel)
{
    __shared__ u16 As[2][128 * 32];
    __shared__ u16 Bs[2][128 * 32];

    const int t = threadIdx.x;
    const int lane = t & 63, wave = t >> 6;
    const int wm = wave >> 1, wn = wave & 1;
    const int l15 = lane & 15, h4 = lane >> 4;
    const int m0 = blockIdx.y * 128, n0 = blockIdx.x * 128;
    const int om = om_sel ? ((mode >= 0) ? mode : *flag) : 0;

    const int r0 = wave * 32 + (lane >> 2);         // staging rows
    const int r1 = r0 + 16;
    const int cs = ((lane & 3) ^ (lane >> 4)) * 8;  // pre-swizzled src chunk
    const u16* Ab0 = A + (size_t)(m0 + r0) * K + cs;
    const u16* Ab1 = A + (size_t)(m0 + r1) * K + cs;
    const u16* Bb0 = Bt + (size_t)(n0 + r0) * K + cs;
    const u16* Bb1 = Bt + (size_t)(n0 + r1) * K + cs;
    const int dst = (wave * 2) * 512;               // u16 offset of slot j=0

    f32x4 acc[4][4];
    #pragma unroll
    for (int i = 0; i < 4; ++i)
        #pragma unroll
        for (int j = 0; j < 4; ++j) acc[i][j] = (f32x4){0.f, 0.f, 0.f, 0.f};

    const int csr = (h4 ^ (l15 >> 2)) * 8;          // swizzled read chunk
    const int arow = wm * 64 + l15;
    const int brow = wn * 64 + l15;

    const int NT = K >> 5;
    // prologue: stage K-tile 0 into buffer 0
    gload16(Ab0, &As[0][dst]);
    gload16(Ab1, &As[0][dst + 512]);
    gload16(Bb0, &Bs[0][dst]);
    gload16(Bb1, &Bs[0][dst + 512]);

    for (int kt = 0; kt < NT; ++kt) {
        const int cur = kt & 1;
        if (kt + 1 < NT) {                          // stage next tile early
            const int k0 = (kt + 1) << 5;
            const int nb = cur ^ 1;
            gload16(Ab0 + k0, &As[nb][dst]);
            gload16(Ab1 + k0, &As[nb][dst + 512]);
            gload16(Bb0 + k0, &Bs[nb][dst]);
            gload16(Bb1 + k0, &Bs[nb][dst + 512]);
            asm volatile("s_waitcnt vmcnt(4)" ::: "memory");  // cur's 4 done
        } else {
            asm volatile("s_waitcnt vmcnt(0)" ::: "memory");
        }
        barrier_raw();                              // cur visible to all

        bf16x8 af[4], bfr[4];
        #pragma unroll
        for (int f = 0; f < 4; ++f) {
            af[f]  = ldsb8(&As[cur][(arow + f * 16) * 32 + csr]);
            bfr[f] = ldsb8(&Bs[cur][(brow + f * 16) * 32 + csr]);
        }
        #pragma unroll
        for (int i = 0; i < 4; ++i)
            #pragma unroll
            for (int j = 0; j < 4; ++j)
                acc[i][j] = mfma16(af[i], bfr[j], acc[i][j]);

        barrier_raw();                              // all done reading cur
    }

    // epilogue: C/D layout col=lane&15, row=(lane>>4)*4+reg
    const int orow = m0 + wm * 64 + h4 * 4;
    const int ocol = n0 + wn * 64 + l15;
    if (om == 0) {
        u16* out = (u16*)outv;
        #pragma unroll
        for (int i = 0; i < 4; ++i)
            #pragma unroll
            for (int j = 0; j < 4; ++j) {
                const int col = ocol + j * 16;
                const float bv = u2f(bias[col]);
                #pragma unroll
                for (int r2 = 0; r2 < 4; ++r2)
                    out[(size_t)(orow + i * 16 + r2) * N + col] = f2b(acc[i][j][r2] + bv);
            }
    } else {
        float* out = (float*)outv;
        #pragma unroll
        for (int i = 0; i < 4; ++i)
            #pragma unroll
            for (int j = 0; j < 4; ++j) {
                const int col = ocol + j * 16;
                const float bv = u2f(bias[col]);
                #pragma unroll
                for (int r2 = 0; r2 < 4; ++r2)
                    out[(size_t)(orow + i * 16 + r2) * N + col] = acc[i][j][r2] + bv;
            }
    }
}

// ---------------------------------------------------------------------------
// MFMA flash attention. Closed-form balanced schedule: bin j's qt triple
// {j, (j+16)&31, j<16?30-2j:63-2j} sums 46/47 -> per-CU work 49/50 tiles.
// V staged as packed b32 pairs into plain Vt[d][k] (2-way, read conflict-
// free); P stored with col XOR swizzle c = k ^ (8*((q>>2)&3)) (2-way).
// ---------------------------------------------------------------------------
__global__ __launch_bounds__(256)
void attn_mfma(const u16* __restrict__ qkv, u16* __restrict__ yatt)
{
    __shared__ u16 Qs[64][72];   // [q][d]  (pre-scaled by 1/8)
    __shared__ u16 Ks[64][72];   // [k][d]
    __shared__ u16 Vt[64][72];   // [d][k]  (plain; packed-pair writes)
    __shared__ u16 Ps[64][72];   // [q][c], c = k ^ (8*((q>>2)&3))

    // ---- balanced work assignment (sums 46/47 per bin, proof in notes) ----
    const int bid = blockIdx.x;
    const int bin = bid & 255, slot = bid >> 8;
    const int g = bin >> 5, j = bin & 31;
    int qt;
    if (slot == 0)      qt = j;
    else if (slot == 1) qt = (j + 16) & 31;
    else                qt = (j < 16) ? (30 - 2 * j) : (63 - 2 * j);
    const int hb = slot * 8 + g;
    const int h = hb % HH, b = hb / HH;

    const int t = threadIdx.x;
    const int lane = t & 63, w = t >> 6;
    const int l15 = lane & 15, h4 = lane >> 4;
    const int q0 = qt * 64;

    const int sr = t >> 2;            // K staging row 0..63
    const int sd = (t & 3) << 4;      // K staging d: 0,16,32,48
    const int vk = (t & 31) * 2;      // V staging k-pair base
    const int vd = (t >> 5) << 3;     // V staging d-chunk: 0..56

    // ---- stage Q tile (scaled by 1/8) ----
    {
        const u16* qp = qkv + ((size_t)(b * TT + q0 + sr)) * C3 + h * DD + sd;
        const u16x8 v0 = *(const u16x8*)qp;
        const u16x8 v1 = *(const u16x8*)(qp + 8);
        u16x8 o0, o1;
        #pragma unroll
        for (int i = 0; i < 8; ++i) {
            o0[i] = f2b(u2f(v0[i]) * 0.125f);
            o1[i] = f2b(u2f(v1[i]) * 0.125f);
        }
        *(u16x8*)&Qs[sr][sd]     = o0;
        *(u16x8*)&Qs[sr][sd + 8] = o1;
    }
    __syncthreads();
    // hoisted loop-invariant Q fragments
    const bf16x8 aq0 = ldsb8(&Qs[w * 16 + l15][h4 * 8]);
    const bf16x8 aq1 = ldsb8(&Qs[w * 16 + l15][32 + h4 * 8]);

    float m_i[4], l_i[4];
    f32x4 O[4];
    #pragma unroll
    for (int r2 = 0; r2 < 4; ++r2) { m_i[r2] = -1e30f; l_i[r2] = 0.f; }
    #pragma unroll
    for (int d = 0; d < 4; ++d) O[d] = (f32x4){0.f, 0.f, 0.f, 0.f};

    const u16* kB  = qkv + ((size_t)(b * TT + sr)) * C3 + CC + h * DD + sd;
    const u16* vB0 = qkv + ((size_t)(b * TT + vk)) * C3 + 2 * CC + h * DD + vd;

    u16x8 kr0 = *(const u16x8*)kB;
    u16x8 kr1 = *(const u16x8*)(kB + 8);
    u16x8 vr0 = *(const u16x8*)vB0;
    u16x8 vr1 = *(const u16x8*)(vB0 + C3);

    const int px = 8 * (h4 ^ ((l15 >> 2) & 3));   // swizzled P read chunk

    const int NT = qt + 1;
    for (int kt = 0; kt < NT; ++kt) {
        __syncthreads();                       // prev tile's compute done
        *(u16x8*)&Ks[sr][sd]     = kr0;
        *(u16x8*)&Ks[sr][sd + 8] = kr1;
        #pragma unroll
        for (int i = 0; i < 8; ++i)            // packed transpose: 8 x b32
            *(u32*)&Vt[vd + i][vk] = (u32)vr0[i] | ((u32)vr1[i] << 16);
        __syncthreads();                       // staging visible

        if (kt + 1 < NT) {                     // next-tile loads before compute
            const u16* kp = kB + (size_t)(kt + 1) * 64 * C3;
            kr0 = *(const u16x8*)kp;
            kr1 = *(const u16x8*)(kp + 8);
            const u16* vp = vB0 + (size_t)(kt + 1) * 64 * C3;
            vr0 = *(const u16x8*)vp;
            vr1 = *(const u16x8*)(vp + C3);
        }

        // ---- S = (Q/8) K^T ----
        f32x4 s[4];
        #pragma unroll
        for (int kf = 0; kf < 4; ++kf) {
            f32x4 z = (f32x4){0.f, 0.f, 0.f, 0.f};
            z = mfma16(aq0, ldsb8(&Ks[kf * 16 + l15][h4 * 8]), z);
            z = mfma16(aq1, ldsb8(&Ks[kf * 16 + l15][32 + h4 * 8]), z);
            s[kf] = z;
        }

        // causal mask: only the diagonal tile needs it
        if (kt == qt) {
            #pragma unroll
            for (int kf = 0; kf < 4; ++kf) {
                const int kg = q0 + kf * 16 + l15;
                #pragma unroll
                for (int r2 = 0; r2 < 4; ++r2) {
                    const int qg = q0 + w * 16 + h4 * 4 + r2;
                    if (kg > qg) s[kf][r2] = -1e30f;
                }
            }
        }

        // ---- online softmax (row = q lives on 16 lanes sharing h4) ----
        float alpha[4];
        #pragma unroll
        for (int r2 = 0; r2 < 4; ++r2) {
            float mx = fmaxf(fmaxf(s[0][r2], s[1][r2]), fmaxf(s[2][r2], s[3][r2]));
            mx = fmaxf(mx, __shfl_xor(mx, 1));
            mx = fmaxf(mx, __shfl_xor(mx, 2));
            mx = fmaxf(mx, __shfl_xor(mx, 4));
            mx = fmaxf(mx, __shfl_xor(mx, 8));       // 16-lane row group
            const float mnew = fmaxf(m_i[r2], mx);
            const float a = __expf(m_i[r2] - mnew);
            const int qrow = w * 16 + h4 * 4 + r2;
            float rs = 0.f;
            #pragma unroll
            for (int kf = 0; kf < 4; ++kf) {
                const float p = __expf(s[kf][r2] - mnew);
                Ps[qrow][(kf * 16 + l15) ^ (h4 * 8)] = f2b(p);
                rs += p;
            }
            rs += __shfl_xor(rs, 1);
            rs += __shfl_xor(rs, 2);
            rs += __shfl_xor(rs, 4);
            rs += __shfl_xor(rs, 8);
            l_i[r2] = l_i[r2] * a + rs;
            m_i[r2] = mnew;
            alpha[r2] = a;
        }
        #pragma unroll
        for (int d = 0; d < 4; ++d)
            #pragma unroll
            for (int r2 = 0; r2 < 4; ++r2) O[d][r2] *= alpha[r2];

        // ---- O += P @ V  (Ps rows wave-private; ds ops in-order per wave) ----
        const bf16x8 ap0 = ldsb8(&Ps[w * 16 + l15][px]);
        const bf16x8 ap1 = ldsb8(&Ps[w * 16 + l15][32 + px]);
        #pragma unroll
        for (int d = 0; d < 4; ++d) {
            O[d] = mfma16(ap0, ldsb8(&Vt[d * 16 + l15][h4 * 8]), O[d]);
            O[d] = mfma16(ap1, ldsb8(&Vt[d * 16 + l15][32 + h4 * 8]), O[d]);
        }
    }

    // ---- epilogue: normalize, store bf16 [B,T,C] ----
    float inv[4];
    #pragma unroll
    for (int r2 = 0; r2 < 4; ++r2) inv[r2] = 1.0f / l_i[r2];
    u16* yp = yatt + ((size_t)(b * TT + q0 + w * 16 + h4 * 4)) * CC + h * DD + l15;
    #pragma unroll
    for (int r2 = 0; r2 < 4; ++r2)
        #pragma unroll
        for (int d = 0; d < 4; ++d)
            yp[(size_t)r2 * CC + d * 16] = f2b(O[d][r2] * inv[r2]);
}

// ---------------------------------------------------------------------------
extern "C" void kernel_launch(void* const* d_in, const int* in_sizes, int n_in,
                              void* d_out, int out_size, void* d_ws, size_t ws_size,
                              hipStream_t stream)
{
    (void)n_in; (void)out_size; (void)ws_size;

    const void* x      = d_in[0];
    const void* W_attn = d_in[1];
    const void* b_attn = d_in[2];
    const void* W_proj = d_in[3];
    const void* b_proj = d_in[4];

    // workspace layout (~30 MB)
    u16* qkv  = (u16*)d_ws;                       // [4096,2304] bf16
    u16* yatt = qkv + (size_t)MM * C3;            // [4096,768]  bf16
    u16* xb   = yatt;                             // bf16 x — lifetime disjoint
    u16* WaT  = yatt + (size_t)MM * CC;           // [2304,768]  bf16 (W_attn^T)
    u16* WpT  = WaT + (size_t)C3 * CC;            // [768,768]   bf16 (W_proj^T)
    u16* ba   = WpT + (size_t)CC * CC;            // [2304] bf16
    u16* bp   = ba + C3;                          // [768]  bf16
    int* flag = (int*)(bp + CC);                  // 1 int

    // host-side dtype inference from byte sizes; device detector as fallback
    int mode = -1;
    if (in_sizes[0] == MM * CC * 4) mode = 1;          // fp32 bytes
    else if (in_sizes[0] == MM * CC * 2) mode = 0;     // bf16 bytes
    if (mode < 0) {
        int nscan = in_sizes[0] < 65536 ? in_sizes[0] : 65536;
        detect_kernel<<<1, 256, 0, stream>>>((const u16*)x, nscan, flag);
    }

    // fused prep: W transposes + x->bf16 + biases
    fused_prep<<<2121, 256, 0, stream>>>(x, W_attn, b_attn, W_proj, b_proj,
                                         xb, WaT, WpT, ba, bp, flag, mode);

    // 1) qkv = xb @ W_attn + b_attn (bf16 out)
    gemm_mfma<<<dim3(C3 / 128, MM / 128), 256, 0, stream>>>(
        xb, WaT, ba, (void*)qkv, MM, C3, CC, flag, mode, 0);

    // 2) causal flash attention (closed-form balanced schedule)
    attn_mfma<<<dim3(TT / 64 * HH * BB, 1, 1), 256, 0, stream>>>(qkv, yatt);

    // 3) out = yatt @ W_proj + b_proj (out dtype follows mode)
    gemm_mfma<<<dim3(CC / 128, MM / 128), 256, 0, stream>>>(
        yatt, WpT, bp, d_out, MM, CC, CC, flag, mode, 1);
}

// Round 4
// 204.575 us; speedup vs baseline: 4.4968x; 1.1160x over previous
//
#include <hip/hip_runtime.h>

// CausalSelfAttention  B=2, T=2048, C=768, H=12, hs=64 — round 4.
// * attn: swapped-S (mfma(K,Q)) + K-row permutation rho(k) so the S output
//   registers ARE the PV A-fragments — P stays in registers, no LDS bounce,
//   softmax is scalar-per-lane (2 reduce shfls). K/V LDS ping-pong with ONE
//   barrier per tile; Q held in registers (no Q LDS, no extra barrier).
// * gemm: templated tile (FR*32): FR=4 (128^2) for QKV, FR=2 (64^2) for the
//   proj GEMM -> 768 blocks instead of 192 (occupancy fix).
// * prep/detect/schedule: unchanged from verified round 3.

#define BB 2
#define TT 2048
#define CC 768
#define C3 2304
#define HH 12
#define DD 64
#define MM 4096   // B*T

typedef unsigned short u16;
typedef unsigned int u32;
typedef __attribute__((ext_vector_type(8))) u16 u16x8;
typedef __attribute__((ext_vector_type(8))) __bf16 bf16x8;
typedef __attribute__((ext_vector_type(4))) float f32x4;

__device__ __forceinline__ float u2f(u16 u) {
    union { u32 i; float f; } c; c.i = ((u32)u) << 16; return c.f;
}
__device__ __forceinline__ u16 f2u(float f) {
    union { float f; u32 i; } c; c.f = f;
    u32 x = c.i;
    return (u16)((x + 0x7FFFu + ((x >> 16) & 1u)) >> 16);  // RNE
}
__device__ __forceinline__ u16 f2b(float f) {              // RNE via v_cvt
    __bf16 h = (__bf16)f; return __builtin_bit_cast(u16, h);
}
__device__ __forceinline__ bf16x8 ldsb8(const u16* p) {
    return __builtin_bit_cast(bf16x8, *(const u16x8*)p);
}
__device__ __forceinline__ f32x4 mfma16(bf16x8 a, bf16x8 b, f32x4 c) {
    return __builtin_amdgcn_mfma_f32_16x16x32_bf16(a, b, c, 0, 0, 0);
}
typedef __attribute__((address_space(1))) const u32 gu32;
typedef __attribute__((address_space(3))) u32 lu32;
__device__ __forceinline__ void gload16(const u16* gp, u16* lp) {
    __builtin_amdgcn_global_load_lds((gu32*)(const void*)gp, (lu32*)(void*)lp,
                                     16, 0, 0);
}
__device__ __forceinline__ void barrier_raw() {
    asm volatile("" ::: "memory");
    __builtin_amdgcn_s_barrier();
    asm volatile("" ::: "memory");
}

// ---------------------------------------------------------------------------
// Fallback detector (only when host can't infer dtype from sizes).
// ---------------------------------------------------------------------------
__global__ void detect_kernel(const u16* __restrict__ x, int nscan,
                              int* __restrict__ flag)
{
    __shared__ int found;
    if (threadIdx.x == 0) found = 0;
    __syncthreads();
    int local = 0;
    for (int i = threadIdx.x; i < nscan; i += 256) {
        if ((x[i] & 0x7F80u) == 0x7F80u) local = 1;
    }
    if (local) atomicOr(&found, 1);
    __syncthreads();
    if (threadIdx.x == 0) *flag = found ? 1 : 0;
}

// ---------------------------------------------------------------------------
// Fused prep: block ranges do {W_attn^T, W_proj^T, x->bf16, biases}.
// ---------------------------------------------------------------------------
__device__ void prep_w_body(const void* __restrict__ Wv, u16* __restrict__ Wt,
                            int K, int N, int bx, int by, int fm,
                            u16 (*Ts)[72])
{
    const int t = threadIdx.x;
    const int n0 = bx * 64, k0 = by * 64;
    const int r = t >> 2, c0 = (t & 3) << 4;

    if (fm) {
        const float* W = (const float*)Wv + (size_t)(k0 + r) * N + n0 + c0;
        #pragma unroll
        for (int i = 0; i < 16; i += 4) {
            const float4 v = *(const float4*)(W + i);
            Ts[c0 + i + 0][r] = f2u(v.x);
            Ts[c0 + i + 1][r] = f2u(v.y);
            Ts[c0 + i + 2][r] = f2u(v.z);
            Ts[c0 + i + 3][r] = f2u(v.w);
        }
    } else {
        const u16* W = (const u16*)Wv + (size_t)(k0 + r) * N + n0 + c0;
        const u16x8 a = *(const u16x8*)W;
        const u16x8 c = *(const u16x8*)(W + 8);
        #pragma unroll
        for (int i = 0; i < 8; ++i) { Ts[c0 + i][r] = a[i]; Ts[c0 + 8 + i][r] = c[i]; }
    }
    __syncthreads();
    u16* o = Wt + (size_t)(n0 + r) * K + k0 + c0;
    *(u16x8*)o = *(const u16x8*)&Ts[r][c0];
    *(u16x8*)(o + 8) = *(const u16x8*)&Ts[r][c0 + 8];
}

__global__ __launch_bounds__(256)
void fused_prep(const void* __restrict__ x, const void* __restrict__ Wa,
                const void* __restrict__ ba, const void* __restrict__ Wp,
                const void* __restrict__ bp,
                u16* __restrict__ xb, u16* __restrict__ WaT,
                u16* __restrict__ WpT, u16* __restrict__ bao,
                u16* __restrict__ bpo,
                const int* __restrict__ flag, int mode)
{
    __shared__ u16 Ts[64][72];
    const int fm = (mode >= 0) ? mode : *flag;
    const int blk = blockIdx.x;
    const int t = threadIdx.x;

    if (blk < 432) {                       // W_attn: grid 36 x 12
        prep_w_body(Wa, WaT, CC, C3, blk % 36, blk / 36, fm, Ts);
    } else if (blk < 576) {                // W_proj: grid 12 x 12
        const int b2 = blk - 432;
        prep_w_body(Wp, WpT, CC, CC, b2 % 12, b2 / 12, fm, Ts);
    } else if (blk < 2112) {               // x -> bf16 (octets)
        const size_t i = (size_t)(blk - 576) * 256 + t;
        if (fm) {
            const float* xp = (const float*)x + i * 8;
            u16x8 o;
            #pragma unroll
            for (int j = 0; j < 8; ++j) o[j] = f2u(xp[j]);
            *(u16x8*)(xb + i * 8) = o;
        } else {
            *(u16x8*)(xb + i * 8) = *(const u16x8*)((const u16*)x + i * 8);
        }
    } else {                               // biases
        const int i = (blk - 2112) * 256 + t;
        if (i < C3) bao[i] = fm ? f2u(((const float*)ba)[i]) : ((const u16*)ba)[i];
        if (i < CC) bpo[i] = fm ? f2u(((const float*)bp)[i]) : ((const u16*)bp)[i];
    }
}

// ---------------------------------------------------------------------------
// MFMA GEMM: out[M][N] = A[M][K] @ Bt[N][K]^T + bias.  A/Bt/bias bf16.
// Tile = (32*FR)^2, BK=32, 4 waves in 2x2, FRxFR frags of 16x16x32 each.
// Double-buffered global_load_lds staging, counted vmcnt, src-side XOR chunk
// swizzle (verified in rounds 2-3; the formulas are FR-invariant).
// ---------------------------------------------------------------------------
template <int FR>
__global__ __launch_bounds__(256)
void gemm_mfma(const u16* __restrict__ A, const u16* __restrict__ Bt,
               const u16* __restrict__ bias, void* __restrict__ outv,
               int M, int N, int K, const int* __restrict__ flag,
               int mode, int om_sel)
{
    constexpr int TS = 32 * FR;       // tile edge
    constexpr int LPW = FR / 2;       // gload16 per wave per matrix

    __shared__ u16 As[2][TS * 32];
    __shared__ u16 Bs[2][TS * 32];

    const int t = threadIdx.x;
    const int lane = t & 63, wave = t >> 6;
    const int wm = wave >> 1, wn = wave & 1;
    const int l15 = lane & 15, h4 = lane >> 4;
    const int m0 = blockIdx.y * TS, n0 = blockIdx.x * TS;
    const int om = om_sel ? ((mode >= 0) ? mode : *flag) : 0;

    // staging: slot s (16B) -> row s>>2, chunk s&3; src chunk XOR-swizzled.
    const int rowA = wave * (TS / 4) + (lane >> 2);      // j adds +16
    const int cs = ((lane & 3) ^ ((lane >> 4) & 3)) * 8;
    const u16* Ab[LPW];
    const u16* Bb[LPW];
    #pragma unroll
    for (int j = 0; j < LPW; ++j) {
        Ab[j] = A + (size_t)(m0 + rowA + 16 * j) * K + cs;
        Bb[j] = Bt + (size_t)(n0 + rowA + 16 * j) * K + cs;
    }
    const int dst = wave * LPW * 512;                    // u16 offset, j adds 512

    f32x4 acc[FR][FR];
    #pragma unroll
    for (int i = 0; i < FR; ++i)
        #pragma unroll
        for (int j = 0; j < FR; ++j) acc[i][j] = (f32x4){0.f, 0.f, 0.f, 0.f};

    const int csr = (h4 ^ (l15 >> 2)) * 8;               // swizzled read chunk
    const int arow = wm * (TS / 2) + l15;
    const int brow = wn * (TS / 2) + l15;

    const int NT = K >> 5;
    #pragma unroll
    for (int j = 0; j < LPW; ++j) {                      // prologue: tile 0
        gload16(Ab[j], &As[0][dst + j * 512]);
        gload16(Bb[j], &Bs[0][dst + j * 512]);
    }

    for (int kt = 0; kt < NT; ++kt) {
        const int cur = kt & 1;
        if (kt + 1 < NT) {                               // stage next tile
            const int k0 = (kt + 1) << 5;
            const int nb = cur ^ 1;
            #pragma unroll
            for (int j = 0; j < LPW; ++j) {
                gload16(Ab[j] + k0, &As[nb][dst + j * 512]);
                gload16(Bb[j] + k0, &Bs[nb][dst + j * 512]);
            }
            if constexpr (FR == 4)
                asm volatile("s_waitcnt vmcnt(4)" ::: "memory");
            else
                asm volatile("s_waitcnt vmcnt(2)" ::: "memory");
        } else {
            asm volatile("s_waitcnt vmcnt(0)" ::: "memory");
        }
        barrier_raw();                                   // cur visible

        bf16x8 af[FR], bfr[FR];
        #pragma unroll
        for (int f = 0; f < FR; ++f) {
            af[f]  = ldsb8(&As[cur][(arow + f * 16) * 32 + csr]);
            bfr[f] = ldsb8(&Bs[cur][(brow + f * 16) * 32 + csr]);
        }
        #pragma unroll
        for (int i = 0; i < FR; ++i)
            #pragma unroll
            for (int j = 0; j < FR; ++j)
                acc[i][j] = mfma16(af[i], bfr[j], acc[i][j]);

        barrier_raw();                                   // done reading cur
    }

    // epilogue: C/D layout col=lane&15, row=(lane>>4)*4+reg
    const int orow = m0 + wm * (TS / 2) + h4 * 4;
    const int ocol = n0 + wn * (TS / 2) + l15;
    if (om == 0) {
        u16* out = (u16*)outv;
        #pragma unroll
        for (int i = 0; i < FR; ++i)
            #pragma unroll
            for (int j = 0; j < FR; ++j) {
                const int col = ocol + j * 16;
                const float bv = u2f(bias[col]);
                #pragma unroll
                for (int r2 = 0; r2 < 4; ++r2)
                    out[(size_t)(orow + i * 16 + r2) * N + col] = f2b(acc[i][j][r2] + bv);
            }
    } else {
        float* out = (float*)outv;
        #pragma unroll
        for (int i = 0; i < FR; ++i)
            #pragma unroll
            for (int j = 0; j < FR; ++j) {
                const int col = ocol + j * 16;
                const float bv = u2f(bias[col]);
                #pragma unroll
                for (int r2 = 0; r2 < 4; ++r2)
                    out[(size_t)(orow + i * 16 + r2) * N + col] = acc[i][j][r2] + bv;
            }
    }
}

// ---------------------------------------------------------------------------
// MFMA flash attention, round 4.
// S computed swapped: s = mfma(K_frag, Q_frag) -> lane owns q = lane&15,
// S row index = k. K rows staged at permuted LDS row rho(k) so lane's 16
// S-registers are exactly the PV A-fragments (k = 8*h4 + i ordering):
//   rho(k) = 32*k5 + 16*k2 + 4*(k4k3) + k1k0
//   lane (q,h4), frag kf, reg r2 holds k = 8*h4 + 32*(kf>>1) + 4*(kf&1) + r2
//   => ap  = {s[0][0..3], s[1][0..3]}  covers k in [8h4, 8h4+8) of [0,32)
//      ap2 = {s[2][0..3], s[3][0..3]}  covers same slots of [32,64)
// Softmax: scalar m/l per lane (q), reduce via shfl_xor 16/32 only.
// K/V LDS ping-pong, ONE barrier per tile, global prefetch 2 tiles deep.
// Q lives in registers (pre-scaled by 1/8). Closed-form balanced schedule
// (verified round 3).
// ---------------------------------------------------------------------------
__global__ __launch_bounds__(256)
void attn_mfma(const u16* __restrict__ qkv, u16* __restrict__ yatt)
{
    __shared__ u16 Ks[2][64][72];   // [buf][rho(k)][d]
    __shared__ u16 Vt[2][64][72];   // [buf][d][k]

    // ---- balanced work assignment (round-3 closed form) ----
    const int bid = blockIdx.x;
    const int bin = bid & 255, slot = bid >> 8;
    const int g = bin >> 5, j = bin & 31;
    int qt;
    if (slot == 0)      qt = j;
    else if (slot == 1) qt = (j + 16) & 31;
    else                qt = (j < 16) ? (30 - 2 * j) : (63 - 2 * j);
    const int hb = slot * 8 + g;
    const int h = hb % HH, b = hb / HH;

    const int t = threadIdx.x;
    const int lane = t & 63, w = t >> 6;
    const int l15 = lane & 15, h4 = lane >> 4;
    const int q0 = qt * 64;

    // K staging: thread covers tile k-row sr, d-chunk sd; LDS row rho(sr).
    const int sr = t >> 2;
    const int sd = (t & 3) << 4;
    const int rho = ((sr >> 5) & 1) * 32 + ((sr >> 2) & 1) * 16 +
                    ((sr >> 3) & 3) * 4 + (sr & 3);
    // V staging: packed b32 k-pairs (round-3 verified, plain [d][k] layout)
    const int vk = (t & 31) * 2;
    const int vd = (t >> 5) << 3;

    // ---- Q in registers, pre-scaled by 1/8 (exact pow2) ----
    bf16x8 aq0, aq1;
    {
        const u16* qp = qkv + ((size_t)(b * TT + q0 + w * 16 + l15)) * C3
                        + h * DD + h4 * 8;
        const u16x8 v0 = *(const u16x8*)qp;
        const u16x8 v1 = *(const u16x8*)(qp + 32);
        #pragma unroll
        for (int i = 0; i < 8; ++i) {
            aq0[i] = (__bf16)(u2f(v0[i]) * 0.125f);
            aq1[i] = (__bf16)(u2f(v1[i]) * 0.125f);
        }
    }

    float m_i = -1e30f, l_i = 0.f;
    f32x4 O[4];
    #pragma unroll
    for (int d = 0; d < 4; ++d) O[d] = (f32x4){0.f, 0.f, 0.f, 0.f};

    const u16* kB = qkv + ((size_t)(b * TT + sr)) * C3 + CC + h * DD + sd;
    const u16* vB = qkv + ((size_t)(b * TT + vk)) * C3 + 2 * CC + h * DD + vd;

    const int NT = qt + 1;

    // ---- prologue: load+stage tile 0, prefetch tile 1 ----
    u16x8 kr0 = *(const u16x8*)kB;
    u16x8 kr1 = *(const u16x8*)(kB + 8);
    u16x8 vr0 = *(const u16x8*)vB;
    u16x8 vr1 = *(const u16x8*)(vB + C3);
    *(u16x8*)&Ks[0][rho][sd]     = kr0;
    *(u16x8*)&Ks[0][rho][sd + 8] = kr1;
    #pragma unroll
    for (int i = 0; i < 8; ++i)
        *(u32*)&Vt[0][vd + i][vk] = (u32)vr0[i] | ((u32)vr1[i] << 16);
    if (NT > 1) {
        const u16* kp = kB + (size_t)64 * C3;
        const u16* vp = vB + (size_t)64 * C3;
        kr0 = *(const u16x8*)kp;
        kr1 = *(const u16x8*)(kp + 8);
        vr0 = *(const u16x8*)vp;
        vr1 = *(const u16x8*)(vp + C3);
    }
    __syncthreads();

    const int qg = q0 + w * 16 + l15;      // this lane's q row (global)

    for (int kt = 0; kt < NT; ++kt) {
        const int cur = kt & 1;

        // ---- S = K Q^T (swapped; scale folded into Q) ----
        f32x4 s[4];
        #pragma unroll
        for (int kf = 0; kf < 4; ++kf) {
            f32x4 z = (f32x4){0.f, 0.f, 0.f, 0.f};
            z = mfma16(ldsb8(&Ks[cur][kf * 16 + l15][h4 * 8]), aq0, z);
            z = mfma16(ldsb8(&Ks[cur][kf * 16 + l15][32 + h4 * 8]), aq1, z);
            s[kf] = z;
        }

        // ---- stage tile kt+1 into the other buffer; prefetch kt+2 ----
        if (kt + 1 < NT) {
            const int nb = cur ^ 1;
            *(u16x8*)&Ks[nb][rho][sd]     = kr0;
            *(u16x8*)&Ks[nb][rho][sd + 8] = kr1;
            #pragma unroll
            for (int i = 0; i < 8; ++i)
                *(u32*)&Vt[nb][vd + i][vk] = (u32)vr0[i] | ((u32)vr1[i] << 16);
            if (kt + 2 < NT) {
                const u16* kp = kB + (size_t)(kt + 2) * 64 * C3;
                const u16* vp = vB + (size_t)(kt + 2) * 64 * C3;
                kr0 = *(const u16x8*)kp;
                kr1 = *(const u16x8*)(kp + 8);
                vr0 = *(const u16x8*)vp;
                vr1 = *(const u16x8*)(vp + C3);
            }
        }

        // ---- causal mask (diagonal tile only); k from the permuted map ----
        if (kt == qt) {
            #pragma unroll
            for (int kf = 0; kf < 4; ++kf) {
                const int kbase = kt * 64 + 8 * h4 + 32 * (kf >> 1) + 4 * (kf & 1);
                #pragma unroll
                for (int r2 = 0; r2 < 4; ++r2)
                    if (kbase + r2 > qg) s[kf][r2] = -1e30f;
            }
        }

        // ---- online softmax: lane owns q = l15; reduce across h4 groups ----
        float mx = s[0][0];
        #pragma unroll
        for (int kf = 0; kf < 4; ++kf)
            #pragma unroll
            for (int r2 = 0; r2 < 4; ++r2) mx = fmaxf(mx, s[kf][r2]);
        mx = fmaxf(mx, __shfl_xor(mx, 16));
        mx = fmaxf(mx, __shfl_xor(mx, 32));
        const float mnew = fmaxf(m_i, mx);
        const float a_ = __expf(m_i - mnew);

        bf16x8 ap, ap2;
        float rs = 0.f;
        #pragma unroll
        for (int kf = 0; kf < 2; ++kf)
            #pragma unroll
            for (int r2 = 0; r2 < 4; ++r2) {
                const float p = __expf(s[kf][r2] - mnew);
                rs += p;
                ap[kf * 4 + r2] = (__bf16)p;
            }
        #pragma unroll
        for (int kf = 2; kf < 4; ++kf)
            #pragma unroll
            for (int r2 = 0; r2 < 4; ++r2) {
                const float p = __expf(s[kf][r2] - mnew);
                rs += p;
                ap2[(kf - 2) * 4 + r2] = (__bf16)p;
            }
        rs += __shfl_xor(rs, 16);
        rs += __shfl_xor(rs, 32);
        l_i = l_i * a_ + rs;
        m_i = mnew;

        // ---- rescale O (alpha broadcast: O rows are q = h4*4+r2 = lane 0-15)
        float alf[4];
        #pragma unroll
        for (int r2 = 0; r2 < 4; ++r2) alf[r2] = __shfl(a_, h4 * 4 + r2);
        #pragma unroll
        for (int d = 0; d < 4; ++d)
            #pragma unroll
            for (int r2 = 0; r2 < 4; ++r2) O[d][r2] *= alf[r2];

        // ---- O += P V (P entirely in registers) ----
        #pragma unroll
        for (int d = 0; d < 4; ++d) {
            O[d] = mfma16(ap,  ldsb8(&Vt[cur][d * 16 + l15][h4 * 8]), O[d]);
            O[d] = mfma16(ap2, ldsb8(&Vt[cur][d * 16 + l15][32 + h4 * 8]), O[d]);
        }

        __syncthreads();                   // one barrier per tile
    }

    // ---- epilogue: normalize (1/l broadcast like alpha), store bf16 ----
    const float invl = 1.0f / l_i;
    float inv[4];
    #pragma unroll
    for (int r2 = 0; r2 < 4; ++r2) inv[r2] = __shfl(invl, h4 * 4 + r2);
    u16* yp = yatt + ((size_t)(b * TT + q0 + w * 16 + h4 * 4)) * CC + h * DD + l15;
    #pragma unroll
    for (int r2 = 0; r2 < 4; ++r2)
        #pragma unroll
        for (int d = 0; d < 4; ++d)
            yp[(size_t)r2 * CC + d * 16] = f2b(O[d][r2] * inv[r2]);
}

// ---------------------------------------------------------------------------
extern "C" void kernel_launch(void* const* d_in, const int* in_sizes, int n_in,
                              void* d_out, int out_size, void* d_ws, size_t ws_size,
                              hipStream_t stream)
{
    (void)n_in; (void)out_size; (void)ws_size;

    const void* x      = d_in[0];
    const void* W_attn = d_in[1];
    const void* b_attn = d_in[2];
    const void* W_proj = d_in[3];
    const void* b_proj = d_in[4];

    // workspace layout (~30 MB)
    u16* qkv  = (u16*)d_ws;                       // [4096,2304] bf16
    u16* yatt = qkv + (size_t)MM * C3;            // [4096,768]  bf16
    u16* xb   = yatt;                             // bf16 x — lifetime disjoint
    u16* WaT  = yatt + (size_t)MM * CC;           // [2304,768]  bf16 (W_attn^T)
    u16* WpT  = WaT + (size_t)C3 * CC;            // [768,768]   bf16 (W_proj^T)
    u16* ba   = WpT + (size_t)CC * CC;            // [2304] bf16
    u16* bp   = ba + C3;                          // [768]  bf16
    int* flag = (int*)(bp + CC);                  // 1 int

    // host-side dtype inference from byte sizes; device detector as fallback
    int mode = -1;
    if (in_sizes[0] == MM * CC * 4) mode = 1;          // fp32 bytes
    else if (in_sizes[0] == MM * CC * 2) mode = 0;     // bf16 bytes
    if (mode < 0) {
        int nscan = in_sizes[0] < 65536 ? in_sizes[0] : 65536;
        detect_kernel<<<1, 256, 0, stream>>>((const u16*)x, nscan, flag);
    }

    // fused prep: W transposes + x->bf16 + biases
    fused_prep<<<2121, 256, 0, stream>>>(x, W_attn, b_attn, W_proj, b_proj,
                                         xb, WaT, WpT, ba, bp, flag, mode);

    // 1) qkv = xb @ W_attn + b_attn (bf16 out), 128^2 tiles
    gemm_mfma<4><<<dim3(C3 / 128, MM / 128), 256, 0, stream>>>(
        xb, WaT, ba, (void*)qkv, MM, C3, CC, flag, mode, 0);

    // 2) causal flash attention
    attn_mfma<<<dim3(TT / 64 * HH * BB, 1, 1), 256, 0, stream>>>(qkv, yatt);

    // 3) out = yatt @ W_proj + b_proj (out dtype follows mode), 64^2 tiles
    gemm_mfma<2><<<dim3(CC / 64, MM / 64), 256, 0, stream>>>(
        yatt, WpT, bp, d_out, MM, CC, CC, flag, mode, 1);
}

// Round 5
// 170.551 us; speedup vs baseline: 5.3939x; 1.1995x over previous
//
#include <hip/hip_runtime.h>

// CausalSelfAttention  B=2, T=2048, C=768, H=12, hs=64 — round 5.
// * detect_kernel: was ~50us (single block, 256 serial scalar loads) and sat
//   on the graph critical path every replay. Now 256 threads x 8 independent
//   u16x8 vector loads (32K words) -> ~2us, same statistical power
//   (P(miss fp32) ~ e^-64).
// * attn: s_setprio(1)/(0) around the QK^T and PV MFMA clusters (T5).
// * all else identical to round-4 verified code.

#define BB 2
#define TT 2048
#define CC 768
#define C3 2304
#define HH 12
#define DD 64
#define MM 4096   // B*T

typedef unsigned short u16;
typedef unsigned int u32;
typedef __attribute__((ext_vector_type(8))) u16 u16x8;
typedef __attribute__((ext_vector_type(8))) __bf16 bf16x8;
typedef __attribute__((ext_vector_type(4))) float f32x4;

__device__ __forceinline__ float u2f(u16 u) {
    union { u32 i; float f; } c; c.i = ((u32)u) << 16; return c.f;
}
__device__ __forceinline__ u16 f2u(float f) {
    union { float f; u32 i; } c; c.f = f;
    u32 x = c.i;
    return (u16)((x + 0x7FFFu + ((x >> 16) & 1u)) >> 16);  // RNE
}
__device__ __forceinline__ u16 f2b(float f) {              // RNE via v_cvt
    __bf16 h = (__bf16)f; return __builtin_bit_cast(u16, h);
}
__device__ __forceinline__ bf16x8 ldsb8(const u16* p) {
    return __builtin_bit_cast(bf16x8, *(const u16x8*)p);
}
__device__ __forceinline__ f32x4 mfma16(bf16x8 a, bf16x8 b, f32x4 c) {
    return __builtin_amdgcn_mfma_f32_16x16x32_bf16(a, b, c, 0, 0, 0);
}
typedef __attribute__((address_space(1))) const u32 gu32;
typedef __attribute__((address_space(3))) u32 lu32;
__device__ __forceinline__ void gload16(const u16* gp, u16* lp) {
    __builtin_amdgcn_global_load_lds((gu32*)(const void*)gp, (lu32*)(void*)lp,
                                     16, 0, 0);
}
__device__ __forceinline__ void barrier_raw() {
    asm volatile("" ::: "memory");
    __builtin_amdgcn_s_barrier();
    asm volatile("" ::: "memory");
}

// ---------------------------------------------------------------------------
// Fast detector: 256 threads x 8 independent u16x8 loads = 32768 words.
// fp32 data: low-half words hit exponent-0xFF with p=1/256 -> ~64 expected
// hits, P(miss) ~ e^-64. bf16 data: 0xFF exponent = inf/nan, absent.
// ---------------------------------------------------------------------------
__global__ void detect_kernel(const u16* __restrict__ x, int* __restrict__ flag)
{
    __shared__ int found;
    if (threadIdx.x == 0) found = 0;
    __syncthreads();
    int local = 0;
    const u16x8* p = (const u16x8*)x + threadIdx.x;
    #pragma unroll
    for (int i = 0; i < 8; ++i) {                  // 8 independent 16B loads
        const u16x8 v = p[(size_t)i * 256];
        #pragma unroll
        for (int j = 0; j < 8; ++j)
            if ((v[j] & 0x7F80u) == 0x7F80u) local = 1;
    }
    if (local) atomicOr(&found, 1);
    __syncthreads();
    if (threadIdx.x == 0) *flag = found ? 1 : 0;
}

// ---------------------------------------------------------------------------
// Fused prep: block ranges do {W_attn^T, W_proj^T, x->bf16, biases}.
// ---------------------------------------------------------------------------
__device__ void prep_w_body(const void* __restrict__ Wv, u16* __restrict__ Wt,
                            int K, int N, int bx, int by, int fm,
                            u16 (*Ts)[72])
{
    const int t = threadIdx.x;
    const int n0 = bx * 64, k0 = by * 64;
    const int r = t >> 2, c0 = (t & 3) << 4;

    if (fm) {
        const float* W = (const float*)Wv + (size_t)(k0 + r) * N + n0 + c0;
        #pragma unroll
        for (int i = 0; i < 16; i += 4) {
            const float4 v = *(const float4*)(W + i);
            Ts[c0 + i + 0][r] = f2u(v.x);
            Ts[c0 + i + 1][r] = f2u(v.y);
            Ts[c0 + i + 2][r] = f2u(v.z);
            Ts[c0 + i + 3][r] = f2u(v.w);
        }
    } else {
        const u16* W = (const u16*)Wv + (size_t)(k0 + r) * N + n0 + c0;
        const u16x8 a = *(const u16x8*)W;
        const u16x8 c = *(const u16x8*)(W + 8);
        #pragma unroll
        for (int i = 0; i < 8; ++i) { Ts[c0 + i][r] = a[i]; Ts[c0 + 8 + i][r] = c[i]; }
    }
    __syncthreads();
    u16* o = Wt + (size_t)(n0 + r) * K + k0 + c0;
    *(u16x8*)o = *(const u16x8*)&Ts[r][c0];
    *(u16x8*)(o + 8) = *(const u16x8*)&Ts[r][c0 + 8];
}

__global__ __launch_bounds__(256)
void fused_prep(const void* __restrict__ x, const void* __restrict__ Wa,
                const void* __restrict__ ba, const void* __restrict__ Wp,
                const void* __restrict__ bp,
                u16* __restrict__ xb, u16* __restrict__ WaT,
                u16* __restrict__ WpT, u16* __restrict__ bao,
                u16* __restrict__ bpo,
                const int* __restrict__ flag, int mode)
{
    __shared__ u16 Ts[64][72];
    const int fm = (mode >= 0) ? mode : *flag;
    const int blk = blockIdx.x;
    const int t = threadIdx.x;

    if (blk < 432) {                       // W_attn: grid 36 x 12
        prep_w_body(Wa, WaT, CC, C3, blk % 36, blk / 36, fm, Ts);
    } else if (blk < 576) {                // W_proj: grid 12 x 12
        const int b2 = blk - 432;
        prep_w_body(Wp, WpT, CC, CC, b2 % 12, b2 / 12, fm, Ts);
    } else if (blk < 2112) {               // x -> bf16 (octets)
        const size_t i = (size_t)(blk - 576) * 256 + t;
        if (fm) {
            const float* xp = (const float*)x + i * 8;
            u16x8 o;
            #pragma unroll
            for (int j = 0; j < 8; ++j) o[j] = f2u(xp[j]);
            *(u16x8*)(xb + i * 8) = o;
        } else {
            *(u16x8*)(xb + i * 8) = *(const u16x8*)((const u16*)x + i * 8);
        }
    } else {                               // biases
        const int i = (blk - 2112) * 256 + t;
        if (i < C3) bao[i] = fm ? f2u(((const float*)ba)[i]) : ((const u16*)ba)[i];
        if (i < CC) bpo[i] = fm ? f2u(((const float*)bp)[i]) : ((const u16*)bp)[i];
    }
}

// ---------------------------------------------------------------------------
// MFMA GEMM: out[M][N] = A[M][K] @ Bt[N][K]^T + bias.  A/Bt/bias bf16.
// Tile = (32*FR)^2, BK=32, 4 waves in 2x2, FRxFR frags of 16x16x32 each.
// Double-buffered global_load_lds staging, counted vmcnt, src-side XOR chunk
// swizzle (verified rounds 2-4).
// ---------------------------------------------------------------------------
template <int FR>
__global__ __launch_bounds__(256)
void gemm_mfma(const u16* __restrict__ A, const u16* __restrict__ Bt,
               const u16* __restrict__ bias, void* __restrict__ outv,
               int M, int N, int K, const int* __restrict__ flag,
               int mode, int om_sel)
{
    constexpr int TS = 32 * FR;       // tile edge
    constexpr int LPW = FR / 2;       // gload16 per wave per matrix

    __shared__ u16 As[2][TS * 32];
    __shared__ u16 Bs[2][TS * 32];

    const int t = threadIdx.x;
    const int lane = t & 63, wave = t >> 6;
    const int wm = wave >> 1, wn = wave & 1;
    const int l15 = lane & 15, h4 = lane >> 4;
    const int m0 = blockIdx.y * TS, n0 = blockIdx.x * TS;
    const int om = om_sel ? ((mode >= 0) ? mode : *flag) : 0;

    const int rowA = wave * (TS / 4) + (lane >> 2);      // j adds +16
    const int cs = ((lane & 3) ^ ((lane >> 4) & 3)) * 8;
    const u16* Ab[LPW];
    const u16* Bb[LPW];
    #pragma unroll
    for (int j = 0; j < LPW; ++j) {
        Ab[j] = A + (size_t)(m0 + rowA + 16 * j) * K + cs;
        Bb[j] = Bt + (size_t)(n0 + rowA + 16 * j) * K + cs;
    }
    const int dst = wave * LPW * 512;                    // u16 offset, j adds 512

    f32x4 acc[FR][FR];
    #pragma unroll
    for (int i = 0; i < FR; ++i)
        #pragma unroll
        for (int j = 0; j < FR; ++j) acc[i][j] = (f32x4){0.f, 0.f, 0.f, 0.f};

    const int csr = (h4 ^ (l15 >> 2)) * 8;               // swizzled read chunk
    const int arow = wm * (TS / 2) + l15;
    const int brow = wn * (TS / 2) + l15;

    const int NT = K >> 5;
    #pragma unroll
    for (int j = 0; j < LPW; ++j) {                      // prologue: tile 0
        gload16(Ab[j], &As[0][dst + j * 512]);
        gload16(Bb[j], &Bs[0][dst + j * 512]);
    }

    for (int kt = 0; kt < NT; ++kt) {
        const int cur = kt & 1;
        if (kt + 1 < NT) {                               // stage next tile
            const int k0 = (kt + 1) << 5;
            const int nb = cur ^ 1;
            #pragma unroll
            for (int j = 0; j < LPW; ++j) {
                gload16(Ab[j] + k0, &As[nb][dst + j * 512]);
                gload16(Bb[j] + k0, &Bs[nb][dst + j * 512]);
            }
            if constexpr (FR == 4)
                asm volatile("s_waitcnt vmcnt(4)" ::: "memory");
            else
                asm volatile("s_waitcnt vmcnt(2)" ::: "memory");
        } else {
            asm volatile("s_waitcnt vmcnt(0)" ::: "memory");
        }
        barrier_raw();                                   // cur visible

        bf16x8 af[FR], bfr[FR];
        #pragma unroll
        for (int f = 0; f < FR; ++f) {
            af[f]  = ldsb8(&As[cur][(arow + f * 16) * 32 + csr]);
            bfr[f] = ldsb8(&Bs[cur][(brow + f * 16) * 32 + csr]);
        }
        #pragma unroll
        for (int i = 0; i < FR; ++i)
            #pragma unroll
            for (int j = 0; j < FR; ++j)
                acc[i][j] = mfma16(af[i], bfr[j], acc[i][j]);

        barrier_raw();                                   // done reading cur
    }

    // epilogue: C/D layout col=lane&15, row=(lane>>4)*4+reg
    const int orow = m0 + wm * (TS / 2) + h4 * 4;
    const int ocol = n0 + wn * (TS / 2) + l15;
    if (om == 0) {
        u16* out = (u16*)outv;
        #pragma unroll
        for (int i = 0; i < FR; ++i)
            #pragma unroll
            for (int j = 0; j < FR; ++j) {
                const int col = ocol + j * 16;
                const float bv = u2f(bias[col]);
                #pragma unroll
                for (int r2 = 0; r2 < 4; ++r2)
                    out[(size_t)(orow + i * 16 + r2) * N + col] = f2b(acc[i][j][r2] + bv);
            }
    } else {
        float* out = (float*)outv;
        #pragma unroll
        for (int i = 0; i < FR; ++i)
            #pragma unroll
            for (int j = 0; j < FR; ++j) {
                const int col = ocol + j * 16;
                const float bv = u2f(bias[col]);
                #pragma unroll
                for (int r2 = 0; r2 < 4; ++r2)
                    out[(size_t)(orow + i * 16 + r2) * N + col] = acc[i][j][r2] + bv;
            }
    }
}

// ---------------------------------------------------------------------------
// MFMA flash attention (round-4 verified structure + T5 setprio).
// Swapped-S + K-row permutation rho(k): S registers ARE the PV A-fragments;
// P never touches LDS. K/V LDS ping-pong, one barrier per tile, 2-deep
// global prefetch, Q in registers, closed-form balanced schedule.
// ---------------------------------------------------------------------------
__global__ __launch_bounds__(256)
void attn_mfma(const u16* __restrict__ qkv, u16* __restrict__ yatt)
{
    __shared__ u16 Ks[2][64][72];   // [buf][rho(k)][d]
    __shared__ u16 Vt[2][64][72];   // [buf][d][k]

    // ---- balanced work assignment (round-3 closed form) ----
    const int bid = blockIdx.x;
    const int bin = bid & 255, slot = bid >> 8;
    const int g = bin >> 5, j = bin & 31;
    int qt;
    if (slot == 0)      qt = j;
    else if (slot == 1) qt = (j + 16) & 31;
    else                qt = (j < 16) ? (30 - 2 * j) : (63 - 2 * j);
    const int hb = slot * 8 + g;
    const int h = hb % HH, b = hb / HH;

    const int t = threadIdx.x;
    const int lane = t & 63, w = t >> 6;
    const int l15 = lane & 15, h4 = lane >> 4;
    const int q0 = qt * 64;

    const int sr = t >> 2;
    const int sd = (t & 3) << 4;
    const int rho = ((sr >> 5) & 1) * 32 + ((sr >> 2) & 1) * 16 +
                    ((sr >> 3) & 3) * 4 + (sr & 3);
    const int vk = (t & 31) * 2;
    const int vd = (t >> 5) << 3;

    // ---- Q in registers, pre-scaled by 1/8 (exact pow2) ----
    bf16x8 aq0, aq1;
    {
        const u16* qp = qkv + ((size_t)(b * TT + q0 + w * 16 + l15)) * C3
                        + h * DD + h4 * 8;
        const u16x8 v0 = *(const u16x8*)qp;
        const u16x8 v1 = *(const u16x8*)(qp + 32);
        #pragma unroll
        for (int i = 0; i < 8; ++i) {
            aq0[i] = (__bf16)(u2f(v0[i]) * 0.125f);
            aq1[i] = (__bf16)(u2f(v1[i]) * 0.125f);
        }
    }

    float m_i = -1e30f, l_i = 0.f;
    f32x4 O[4];
    #pragma unroll
    for (int d = 0; d < 4; ++d) O[d] = (f32x4){0.f, 0.f, 0.f, 0.f};

    const u16* kB = qkv + ((size_t)(b * TT + sr)) * C3 + CC + h * DD + sd;
    const u16* vB = qkv + ((size_t)(b * TT + vk)) * C3 + 2 * CC + h * DD + vd;

    const int NT = qt + 1;

    // ---- prologue: load+stage tile 0, prefetch tile 1 ----
    u16x8 kr0 = *(const u16x8*)kB;
    u16x8 kr1 = *(const u16x8*)(kB + 8);
    u16x8 vr0 = *(const u16x8*)vB;
    u16x8 vr1 = *(const u16x8*)(vB + C3);
    *(u16x8*)&Ks[0][rho][sd]     = kr0;
    *(u16x8*)&Ks[0][rho][sd + 8] = kr1;
    #pragma unroll
    for (int i = 0; i < 8; ++i)
        *(u32*)&Vt[0][vd + i][vk] = (u32)vr0[i] | ((u32)vr1[i] << 16);
    if (NT > 1) {
        const u16* kp = kB + (size_t)64 * C3;
        const u16* vp = vB + (size_t)64 * C3;
        kr0 = *(const u16x8*)kp;
        kr1 = *(const u16x8*)(kp + 8);
        vr0 = *(const u16x8*)vp;
        vr1 = *(const u16x8*)(vp + C3);
    }
    __syncthreads();

    const int qg = q0 + w * 16 + l15;      // this lane's q row (global)

    for (int kt = 0; kt < NT; ++kt) {
        const int cur = kt & 1;

        // ---- S = K Q^T (swapped; scale folded into Q) ----
        f32x4 s[4];
        __builtin_amdgcn_s_setprio(1);
        #pragma unroll
        for (int kf = 0; kf < 4; ++kf) {
            f32x4 z = (f32x4){0.f, 0.f, 0.f, 0.f};
            z = mfma16(ldsb8(&Ks[cur][kf * 16 + l15][h4 * 8]), aq0, z);
            z = mfma16(ldsb8(&Ks[cur][kf * 16 + l15][32 + h4 * 8]), aq1, z);
            s[kf] = z;
        }
        __builtin_amdgcn_s_setprio(0);

        // ---- stage tile kt+1 into the other buffer; prefetch kt+2 ----
        if (kt + 1 < NT) {
            const int nb = cur ^ 1;
            *(u16x8*)&Ks[nb][rho][sd]     = kr0;
            *(u16x8*)&Ks[nb][rho][sd + 8] = kr1;
            #pragma unroll
            for (int i = 0; i < 8; ++i)
                *(u32*)&Vt[nb][vd + i][vk] = (u32)vr0[i] | ((u32)vr1[i] << 16);
            if (kt + 2 < NT) {
                const u16* kp = kB + (size_t)(kt + 2) * 64 * C3;
                const u16* vp = vB + (size_t)(kt + 2) * 64 * C3;
                kr0 = *(const u16x8*)kp;
                kr1 = *(const u16x8*)(kp + 8);
                vr0 = *(const u16x8*)vp;
                vr1 = *(const u16x8*)(vp + C3);
            }
        }

        // ---- causal mask (diagonal tile only); k from the permuted map ----
        if (kt == qt) {
            #pragma unroll
            for (int kf = 0; kf < 4; ++kf) {
                const int kbase = kt * 64 + 8 * h4 + 32 * (kf >> 1) + 4 * (kf & 1);
                #pragma unroll
                for (int r2 = 0; r2 < 4; ++r2)
                    if (kbase + r2 > qg) s[kf][r2] = -1e30f;
            }
        }

        // ---- online softmax: lane owns q = l15; reduce across h4 groups ----
        float mx = s[0][0];
        #pragma unroll
        for (int kf = 0; kf < 4; ++kf)
            #pragma unroll
            for (int r2 = 0; r2 < 4; ++r2) mx = fmaxf(mx, s[kf][r2]);
        mx = fmaxf(mx, __shfl_xor(mx, 16));
        mx = fmaxf(mx, __shfl_xor(mx, 32));
        const float mnew = fmaxf(m_i, mx);
        const float a_ = __expf(m_i - mnew);

        bf16x8 ap, ap2;
        float rs = 0.f;
        #pragma unroll
        for (int kf = 0; kf < 2; ++kf)
            #pragma unroll
            for (int r2 = 0; r2 < 4; ++r2) {
                const float p = __expf(s[kf][r2] - mnew);
                rs += p;
                ap[kf * 4 + r2] = (__bf16)p;
            }
        #pragma unroll
        for (int kf = 2; kf < 4; ++kf)
            #pragma unroll
            for (int r2 = 0; r2 < 4; ++r2) {
                const float p = __expf(s[kf][r2] - mnew);
                rs += p;
                ap2[(kf - 2) * 4 + r2] = (__bf16)p;
            }
        rs += __shfl_xor(rs, 16);
        rs += __shfl_xor(rs, 32);
        l_i = l_i * a_ + rs;
        m_i = mnew;

        // ---- rescale O (alpha broadcast: O rows are q = h4*4+r2 = lane 0-15)
        float alf[4];
        #pragma unroll
        for (int r2 = 0; r2 < 4; ++r2) alf[r2] = __shfl(a_, h4 * 4 + r2);
        #pragma unroll
        for (int d = 0; d < 4; ++d)
            #pragma unroll
            for (int r2 = 0; r2 < 4; ++r2) O[d][r2] *= alf[r2];

        // ---- O += P V (P entirely in registers) ----
        __builtin_amdgcn_s_setprio(1);
        #pragma unroll
        for (int d = 0; d < 4; ++d) {
            O[d] = mfma16(ap,  ldsb8(&Vt[cur][d * 16 + l15][h4 * 8]), O[d]);
            O[d] = mfma16(ap2, ldsb8(&Vt[cur][d * 16 + l15][32 + h4 * 8]), O[d]);
        }
        __builtin_amdgcn_s_setprio(0);

        __syncthreads();                   // one barrier per tile
    }

    // ---- epilogue: normalize (1/l broadcast like alpha), store bf16 ----
    const float invl = 1.0f / l_i;
    float inv[4];
    #pragma unroll
    for (int r2 = 0; r2 < 4; ++r2) inv[r2] = __shfl(invl, h4 * 4 + r2);
    u16* yp = yatt + ((size_t)(b * TT + q0 + w * 16 + h4 * 4)) * CC + h * DD + l15;
    #pragma unroll
    for (int r2 = 0; r2 < 4; ++r2)
        #pragma unroll
        for (int d = 0; d < 4; ++d)
            yp[(size_t)r2 * CC + d * 16] = f2b(O[d][r2] * inv[r2]);
}

// ---------------------------------------------------------------------------
extern "C" void kernel_launch(void* const* d_in, const int* in_sizes, int n_in,
                              void* d_out, int out_size, void* d_ws, size_t ws_size,
                              hipStream_t stream)
{
    (void)n_in; (void)out_size; (void)ws_size;

    const void* x      = d_in[0];
    const void* W_attn = d_in[1];
    const void* b_attn = d_in[2];
    const void* W_proj = d_in[3];
    const void* b_proj = d_in[4];

    // workspace layout (~30 MB)
    u16* qkv  = (u16*)d_ws;                       // [4096,2304] bf16
    u16* yatt = qkv + (size_t)MM * C3;            // [4096,768]  bf16
    u16* xb   = yatt;                             // bf16 x — lifetime disjoint
    u16* WaT  = yatt + (size_t)MM * CC;           // [2304,768]  bf16 (W_attn^T)
    u16* WpT  = WaT + (size_t)C3 * CC;            // [768,768]   bf16 (W_proj^T)
    u16* ba   = WpT + (size_t)CC * CC;            // [2304] bf16
    u16* bp   = ba + C3;                          // [768]  bf16
    int* flag = (int*)(bp + CC);                  // 1 int

    // host-side dtype inference from byte sizes; device detector as fallback
    int mode = -1;
    if (in_sizes[0] == MM * CC * 4) mode = 1;          // fp32 bytes
    else if (in_sizes[0] == MM * CC * 2) mode = 0;     // bf16 bytes
    if (mode < 0) {
        detect_kernel<<<1, 256, 0, stream>>>((const u16*)x, flag);
    }

    // fused prep: W transposes + x->bf16 + biases
    fused_prep<<<2121, 256, 0, stream>>>(x, W_attn, b_attn, W_proj, b_proj,
                                         xb, WaT, WpT, ba, bp, flag, mode);

    // 1) qkv = xb @ W_attn + b_attn (bf16 out), 128^2 tiles
    gemm_mfma<4><<<dim3(C3 / 128, MM / 128), 256, 0, stream>>>(
        xb, WaT, ba, (void*)qkv, MM, C3, CC, flag, mode, 0);

    // 2) causal flash attention
    attn_mfma<<<dim3(TT / 64 * HH * BB, 1, 1), 256, 0, stream>>>(qkv, yatt);

    // 3) out = yatt @ W_proj + b_proj (out dtype follows mode), 64^2 tiles
    gemm_mfma<2><<<dim3(CC / 64, MM / 64), 256, 0, stream>>>(
        yatt, WpT, bp, d_out, MM, CC, CC, flag, mode, 1);
}

// Round 7
// 162.894 us; speedup vs baseline: 5.6474x; 1.0470x over previous
//
#include <hip/hip_runtime.h>

// CausalSelfAttention  B=2, T=2048, C=768, H=12, hs=64 — round 7
// (identical resubmit of round 6; that bench died to a container-acquisition
// infra failure with no kernel signal).
// * attn: defer-max (THR=8) + per-lane partial l (epilogue reduce) ->
//   steady-state softmax has ZERO cross-lane ops (was 8 shfls/tile).
// * gemm: generalized FRM x FRN tiles; QKV = 128x64 (1152 blocks, 4.5/CU,
//   was 576 @ 2.25/CU with 25% tail waste); bijective XCD swizzle.
// * x->bf16 copy skipped when input already bf16 (A-pointer runtime select).
// * detect (fast vector scan), prep, schedule: round-5 verified.

#define BB 2
#define TT 2048
#define CC 768
#define C3 2304
#define HH 12
#define DD 64
#define MM 4096   // B*T

typedef unsigned short u16;
typedef unsigned int u32;
typedef __attribute__((ext_vector_type(8))) u16 u16x8;
typedef __attribute__((ext_vector_type(8))) __bf16 bf16x8;
typedef __attribute__((ext_vector_type(4))) float f32x4;

__device__ __forceinline__ float u2f(u16 u) {
    union { u32 i; float f; } c; c.i = ((u32)u) << 16; return c.f;
}
__device__ __forceinline__ u16 f2u(float f) {
    union { float f; u32 i; } c; c.f = f;
    u32 x = c.i;
    return (u16)((x + 0x7FFFu + ((x >> 16) & 1u)) >> 16);  // RNE
}
__device__ __forceinline__ u16 f2b(float f) {              // RNE via v_cvt
    __bf16 h = (__bf16)f; return __builtin_bit_cast(u16, h);
}
__device__ __forceinline__ bf16x8 ldsb8(const u16* p) {
    return __builtin_bit_cast(bf16x8, *(const u16x8*)p);
}
__device__ __forceinline__ f32x4 mfma16(bf16x8 a, bf16x8 b, f32x4 c) {
    return __builtin_amdgcn_mfma_f32_16x16x32_bf16(a, b, c, 0, 0, 0);
}
typedef __attribute__((address_space(1))) const u32 gu32;
typedef __attribute__((address_space(3))) u32 lu32;
__device__ __forceinline__ void gload16(const u16* gp, u16* lp) {
    __builtin_amdgcn_global_load_lds((gu32*)(const void*)gp, (lu32*)(void*)lp,
                                     16, 0, 0);
}
__device__ __forceinline__ void barrier_raw() {
    asm volatile("" ::: "memory");
    __builtin_amdgcn_s_barrier();
    asm volatile("" ::: "memory");
}

// ---------------------------------------------------------------------------
// Fast detector: 256 threads x 8 independent u16x8 loads = 32768 words.
// fp32 data: low-half words hit exponent-0xFF with p=1/256 -> ~64 expected
// hits, P(miss) ~ e^-64. bf16 data: 0xFF exponent = inf/nan, absent.
// ---------------------------------------------------------------------------
__global__ void detect_kernel(const u16* __restrict__ x, int* __restrict__ flag)
{
    __shared__ int found;
    if (threadIdx.x == 0) found = 0;
    __syncthreads();
    int local = 0;
    const u16x8* p = (const u16x8*)x + threadIdx.x;
    #pragma unroll
    for (int i = 0; i < 8; ++i) {                  // 8 independent 16B loads
        const u16x8 v = p[(size_t)i * 256];
        #pragma unroll
        for (int j = 0; j < 8; ++j)
            if ((v[j] & 0x7F80u) == 0x7F80u) local = 1;
    }
    if (local) atomicOr(&found, 1);
    __syncthreads();
    if (threadIdx.x == 0) *flag = found ? 1 : 0;
}

// ---------------------------------------------------------------------------
// Fused prep: block ranges do {W_attn^T, W_proj^T, x->bf16, biases}.
// x->bf16 blocks early-out when input is already bf16 (gemm reads x direct).
// ---------------------------------------------------------------------------
__device__ void prep_w_body(const void* __restrict__ Wv, u16* __restrict__ Wt,
                            int K, int N, int bx, int by, int fm,
                            u16 (*Ts)[72])
{
    const int t = threadIdx.x;
    const int n0 = bx * 64, k0 = by * 64;
    const int r = t >> 2, c0 = (t & 3) << 4;

    if (fm) {
        const float* W = (const float*)Wv + (size_t)(k0 + r) * N + n0 + c0;
        #pragma unroll
        for (int i = 0; i < 16; i += 4) {
            const float4 v = *(const float4*)(W + i);
            Ts[c0 + i + 0][r] = f2u(v.x);
            Ts[c0 + i + 1][r] = f2u(v.y);
            Ts[c0 + i + 2][r] = f2u(v.z);
            Ts[c0 + i + 3][r] = f2u(v.w);
        }
    } else {
        const u16* W = (const u16*)Wv + (size_t)(k0 + r) * N + n0 + c0;
        const u16x8 a = *(const u16x8*)W;
        const u16x8 c = *(const u16x8*)(W + 8);
        #pragma unroll
        for (int i = 0; i < 8; ++i) { Ts[c0 + i][r] = a[i]; Ts[c0 + 8 + i][r] = c[i]; }
    }
    __syncthreads();
    u16* o = Wt + (size_t)(n0 + r) * K + k0 + c0;
    *(u16x8*)o = *(const u16x8*)&Ts[r][c0];
    *(u16x8*)(o + 8) = *(const u16x8*)&Ts[r][c0 + 8];
}

__global__ __launch_bounds__(256)
void fused_prep(const void* __restrict__ x, const void* __restrict__ Wa,
                const void* __restrict__ ba, const void* __restrict__ Wp,
                const void* __restrict__ bp,
                u16* __restrict__ xb, u16* __restrict__ WaT,
                u16* __restrict__ WpT, u16* __restrict__ bao,
                u16* __restrict__ bpo,
                const int* __restrict__ flag, int mode)
{
    __shared__ u16 Ts[64][72];
    const int fm = (mode >= 0) ? mode : *flag;
    const int blk = blockIdx.x;
    const int t = threadIdx.x;

    if (blk < 432) {                       // W_attn: grid 36 x 12
        prep_w_body(Wa, WaT, CC, C3, blk % 36, blk / 36, fm, Ts);
    } else if (blk < 576) {                // W_proj: grid 12 x 12
        const int b2 = blk - 432;
        prep_w_body(Wp, WpT, CC, CC, b2 % 12, b2 / 12, fm, Ts);
    } else if (blk < 2112) {               // x -> bf16 (octets), fp32 mode only
        if (fm == 0) return;
        const size_t i = (size_t)(blk - 576) * 256 + t;
        const float* xp = (const float*)x + i * 8;
        u16x8 o;
        #pragma unroll
        for (int j = 0; j < 8; ++j) o[j] = f2u(xp[j]);
        *(u16x8*)(xb + i * 8) = o;
    } else {                               // biases
        const int i = (blk - 2112) * 256 + t;
        if (i < C3) bao[i] = fm ? f2u(((const float*)ba)[i]) : ((const u16*)ba)[i];
        if (i < CC) bpo[i] = fm ? f2u(((const float*)bp)[i]) : ((const u16*)bp)[i];
    }
}

// ---------------------------------------------------------------------------
// MFMA GEMM: out[M][N] = A[M][K] @ Bt[N][K]^T + bias.  A/Bt/bias bf16.
// Tile = (32*FRM) x (32*FRN), BK=32, 4 waves in 2x2, FRMxFRN frags each.
// Double-buffered global_load_lds staging, counted vmcnt, src-side XOR chunk
// swizzle (verified rounds 2-5; formulas invariant in FRM/FRN since all row
// bases are multiples of 16). Linear grid + bijective XCD swizzle (nwg%8==0).
// A-pointer selected at runtime: fm ? Acnv (bf16-converted) : Adir (raw bf16).
// ---------------------------------------------------------------------------
template <int FRM, int FRN>
__global__ __launch_bounds__(256)
void gemm_mfma(const u16* __restrict__ Adir, const u16* __restrict__ Acnv,
               const u16* __restrict__ Bt, const u16* __restrict__ bias,
               void* __restrict__ outv, int M, int N, int K,
               const int* __restrict__ flag, int mode, int om_sel)
{
    constexpr int TSM = 32 * FRM, TSN = 32 * FRN;
    constexpr int LPA = TSM / 64;     // gload16 per wave for A
    constexpr int LPB = TSN / 64;     // gload16 per wave for B

    __shared__ u16 As[2][TSM * 32];
    __shared__ u16 Bs[2][TSN * 32];

    const int fm = (mode >= 0) ? mode : *flag;
    const u16* A = fm ? Acnv : Adir;
    const int om = om_sel ? fm : 0;

    // bijective XCD swizzle on the linear grid
    const int nwg = gridDim.x;
    const int lin = (blockIdx.x & 7) * (nwg >> 3) + (blockIdx.x >> 3);
    const int nx = N / TSN;
    const int m0 = (lin / nx) * TSM, n0 = (lin % nx) * TSN;

    const int t = threadIdx.x;
    const int lane = t & 63, wave = t >> 6;
    const int wm = wave >> 1, wn = wave & 1;
    const int l15 = lane & 15, h4 = lane >> 4;

    const int rsub = lane >> 2;
    const int cs = ((lane & 3) ^ ((lane >> 4) & 3)) * 8;   // swizzled src chunk
    const u16* Ab[LPA];
    const u16* Bb[LPB];
    #pragma unroll
    for (int j = 0; j < LPA; ++j)
        Ab[j] = A + (size_t)(m0 + wave * (16 * LPA) + j * 16 + rsub) * K + cs;
    #pragma unroll
    for (int j = 0; j < LPB; ++j)
        Bb[j] = Bt + (size_t)(n0 + wave * (16 * LPB) + j * 16 + rsub) * K + cs;

    f32x4 acc[FRM][FRN];
    #pragma unroll
    for (int i = 0; i < FRM; ++i)
        #pragma unroll
        for (int j = 0; j < FRN; ++j) acc[i][j] = (f32x4){0.f, 0.f, 0.f, 0.f};

    const int csr = (h4 ^ (l15 >> 2)) * 8;                 // swizzled read chunk
    const int arow = wm * (TSM / 2) + l15;
    const int brow = wn * (TSN / 2) + l15;

    const int NT = K >> 5;
    #pragma unroll
    for (int j = 0; j < LPA; ++j)                          // prologue: tile 0
        gload16(Ab[j], &As[0][(wave * LPA + j) * 512]);
    #pragma unroll
    for (int j = 0; j < LPB; ++j)
        gload16(Bb[j], &Bs[0][(wave * LPB + j) * 512]);

    for (int kt = 0; kt < NT; ++kt) {
        const int cur = kt & 1;
        if (kt + 1 < NT) {                                 // stage next tile
            const int k0 = (kt + 1) << 5;
            const int nb = cur ^ 1;
            #pragma unroll
            for (int j = 0; j < LPA; ++j)
                gload16(Ab[j] + k0, &As[nb][(wave * LPA + j) * 512]);
            #pragma unroll
            for (int j = 0; j < LPB; ++j)
                gload16(Bb[j] + k0, &Bs[nb][(wave * LPB + j) * 512]);
            if constexpr (LPA + LPB == 4)
                asm volatile("s_waitcnt vmcnt(4)" ::: "memory");
            else if constexpr (LPA + LPB == 3)
                asm volatile("s_waitcnt vmcnt(3)" ::: "memory");
            else
                asm volatile("s_waitcnt vmcnt(2)" ::: "memory");
        } else {
            asm volatile("s_waitcnt vmcnt(0)" ::: "memory");
        }
        barrier_raw();                                     // cur visible

        bf16x8 af[FRM], bfr[FRN];
        #pragma unroll
        for (int f = 0; f < FRM; ++f)
            af[f] = ldsb8(&As[cur][(arow + f * 16) * 32 + csr]);
        #pragma unroll
        for (int f = 0; f < FRN; ++f)
            bfr[f] = ldsb8(&Bs[cur][(brow + f * 16) * 32 + csr]);
        #pragma unroll
        for (int i = 0; i < FRM; ++i)
            #pragma unroll
            for (int j = 0; j < FRN; ++j)
                acc[i][j] = mfma16(af[i], bfr[j], acc[i][j]);

        barrier_raw();                                     // done reading cur
    }

    // epilogue: C/D layout col=lane&15, row=(lane>>4)*4+reg
    const int orow = m0 + wm * (TSM / 2) + h4 * 4;
    const int ocol = n0 + wn * (TSN / 2) + l15;
    if (om == 0) {
        u16* out = (u16*)outv;
        #pragma unroll
        for (int i = 0; i < FRM; ++i)
            #pragma unroll
            for (int j = 0; j < FRN; ++j) {
                const int col = ocol + j * 16;
                const float bv = u2f(bias[col]);
                #pragma unroll
                for (int r2 = 0; r2 < 4; ++r2)
                    out[(size_t)(orow + i * 16 + r2) * N + col] = f2b(acc[i][j][r2] + bv);
            }
    } else {
        float* out = (float*)outv;
        #pragma unroll
        for (int i = 0; i < FRM; ++i)
            #pragma unroll
            for (int j = 0; j < FRN; ++j) {
                const int col = ocol + j * 16;
                const float bv = u2f(bias[col]);
                #pragma unroll
                for (int r2 = 0; r2 < 4; ++r2)
                    out[(size_t)(orow + i * 16 + r2) * N + col] = acc[i][j][r2] + bv;
            }
    }
}

// ---------------------------------------------------------------------------
// MFMA flash attention (round-5 verified structure + shfl-free softmax).
// Swapped-S + K-row permutation rho(k): S registers ARE the PV A-fragments.
// Defer-max (THR=8): exp base m_i raised only when !__all(local_max<=m_i+8);
// rescale (4 shfls + 16 muls + exp) is a rare wave-uniform branch.
// l kept as PER-LANE PARTIAL (this lane's 16 k-slots); reduced once in the
// epilogue. Steady-state tile: zero cross-lane operations in softmax.
// ---------------------------------------------------------------------------
__global__ __launch_bounds__(256)
void attn_mfma(const u16* __restrict__ qkv, u16* __restrict__ yatt)
{
    __shared__ u16 Ks[2][64][72];   // [buf][rho(k)][d]
    __shared__ u16 Vt[2][64][72];   // [buf][d][k]

    // ---- balanced work assignment (round-3 closed form) ----
    const int bid = blockIdx.x;
    const int bin = bid & 255, slot = bid >> 8;
    const int g = bin >> 5, j = bin & 31;
    int qt;
    if (slot == 0)      qt = j;
    else if (slot == 1) qt = (j + 16) & 31;
    else                qt = (j < 16) ? (30 - 2 * j) : (63 - 2 * j);
    const int hb = slot * 8 + g;
    const int h = hb % HH, b = hb / HH;

    const int t = threadIdx.x;
    const int lane = t & 63, w = t >> 6;
    const int l15 = lane & 15, h4 = lane >> 4;
    const int q0 = qt * 64;

    const int sr = t >> 2;
    const int sd = (t & 3) << 4;
    const int rho = ((sr >> 5) & 1) * 32 + ((sr >> 2) & 1) * 16 +
                    ((sr >> 3) & 3) * 4 + (sr & 3);
    const int vk = (t & 31) * 2;
    const int vd = (t >> 5) << 3;

    // ---- Q in registers, pre-scaled by 1/8 (exact pow2) ----
    bf16x8 aq0, aq1;
    {
        const u16* qp = qkv + ((size_t)(b * TT + q0 + w * 16 + l15)) * C3
                        + h * DD + h4 * 8;
        const u16x8 v0 = *(const u16x8*)qp;
        const u16x8 v1 = *(const u16x8*)(qp + 32);
        #pragma unroll
        for (int i = 0; i < 8; ++i) {
            aq0[i] = (__bf16)(u2f(v0[i]) * 0.125f);
            aq1[i] = (__bf16)(u2f(v1[i]) * 0.125f);
        }
    }

    float m_i = -1e30f, l_p = 0.f;     // m: row exp-base; l_p: PER-LANE partial
    f32x4 O[4];
    #pragma unroll
    for (int d = 0; d < 4; ++d) O[d] = (f32x4){0.f, 0.f, 0.f, 0.f};

    const u16* kB = qkv + ((size_t)(b * TT + sr)) * C3 + CC + h * DD + sd;
    const u16* vB = qkv + ((size_t)(b * TT + vk)) * C3 + 2 * CC + h * DD + vd;

    const int NT = qt + 1;

    // ---- prologue: load+stage tile 0, prefetch tile 1 ----
    u16x8 kr0 = *(const u16x8*)kB;
    u16x8 kr1 = *(const u16x8*)(kB + 8);
    u16x8 vr0 = *(const u16x8*)vB;
    u16x8 vr1 = *(const u16x8*)(vB + C3);
    *(u16x8*)&Ks[0][rho][sd]     = kr0;
    *(u16x8*)&Ks[0][rho][sd + 8] = kr1;
    #pragma unroll
    for (int i = 0; i < 8; ++i)
        *(u32*)&Vt[0][vd + i][vk] = (u32)vr0[i] | ((u32)vr1[i] << 16);
    if (NT > 1) {
        const u16* kp = kB + (size_t)64 * C3;
        const u16* vp = vB + (size_t)64 * C3;
        kr0 = *(const u16x8*)kp;
        kr1 = *(const u16x8*)(kp + 8);
        vr0 = *(const u16x8*)vp;
        vr1 = *(const u16x8*)(vp + C3);
    }
    __syncthreads();

    const int qg = q0 + w * 16 + l15;      // this lane's q row (global)

    for (int kt = 0; kt < NT; ++kt) {
        const int cur = kt & 1;

        // ---- S = K Q^T (swapped; scale folded into Q) ----
        f32x4 s[4];
        __builtin_amdgcn_s_setprio(1);
        #pragma unroll
        for (int kf = 0; kf < 4; ++kf) {
            f32x4 z = (f32x4){0.f, 0.f, 0.f, 0.f};
            z = mfma16(ldsb8(&Ks[cur][kf * 16 + l15][h4 * 8]), aq0, z);
            z = mfma16(ldsb8(&Ks[cur][kf * 16 + l15][32 + h4 * 8]), aq1, z);
            s[kf] = z;
        }
        __builtin_amdgcn_s_setprio(0);

        // ---- stage tile kt+1 into the other buffer; prefetch kt+2 ----
        if (kt + 1 < NT) {
            const int nb = cur ^ 1;
            *(u16x8*)&Ks[nb][rho][sd]     = kr0;
            *(u16x8*)&Ks[nb][rho][sd + 8] = kr1;
            #pragma unroll
            for (int i = 0; i < 8; ++i)
                *(u32*)&Vt[nb][vd + i][vk] = (u32)vr0[i] | ((u32)vr1[i] << 16);
            if (kt + 2 < NT) {
                const u16* kp = kB + (size_t)(kt + 2) * 64 * C3;
                const u16* vp = vB + (size_t)(kt + 2) * 64 * C3;
                kr0 = *(const u16x8*)kp;
                kr1 = *(const u16x8*)(kp + 8);
                vr0 = *(const u16x8*)vp;
                vr1 = *(const u16x8*)(vp + C3);
            }
        }

        // ---- causal mask (diagonal tile only); k from the permuted map ----
        if (kt == qt) {
            #pragma unroll
            for (int kf = 0; kf < 4; ++kf) {
                const int kbase = kt * 64 + 8 * h4 + 32 * (kf >> 1) + 4 * (kf & 1);
                #pragma unroll
                for (int r2 = 0; r2 < 4; ++r2)
                    if (kbase + r2 > qg) s[kf][r2] = -1e30f;
            }
        }

        // ---- softmax, defer-max: no cross-lane ops in the common path ----
        float pm = s[0][0];
        #pragma unroll
        for (int kf = 0; kf < 4; ++kf)
            #pragma unroll
            for (int r2 = 0; r2 < 4; ++r2) pm = fmaxf(pm, s[kf][r2]);

        if (!__all(pm <= m_i + 8.f)) {     // rare: raise base and rescale
            float pr = pm;
            pr = fmaxf(pr, __shfl_xor(pr, 16));
            pr = fmaxf(pr, __shfl_xor(pr, 32));
            const float mnew = fmaxf(m_i, pr);
            const float a_ = __expf(m_i - mnew);
            l_p *= a_;
            float alf[4];
            #pragma unroll
            for (int r2 = 0; r2 < 4; ++r2) alf[r2] = __shfl(a_, h4 * 4 + r2);
            #pragma unroll
            for (int d = 0; d < 4; ++d)
                #pragma unroll
                for (int r2 = 0; r2 < 4; ++r2) O[d][r2] *= alf[r2];
            m_i = mnew;
        }

        bf16x8 ap, ap2;
        float rs = 0.f;
        #pragma unroll
        for (int kf = 0; kf < 2; ++kf)
            #pragma unroll
            for (int r2 = 0; r2 < 4; ++r2) {
                const float p = __expf(s[kf][r2] - m_i);
                rs += p;
                ap[kf * 4 + r2] = (__bf16)p;
            }
        #pragma unroll
        for (int kf = 2; kf < 4; ++kf)
            #pragma unroll
            for (int r2 = 0; r2 < 4; ++r2) {
                const float p = __expf(s[kf][r2] - m_i);
                rs += p;
                ap2[(kf - 2) * 4 + r2] = (__bf16)p;
            }
        l_p += rs;                         // per-lane partial; reduced at end

        // ---- O += P V (P entirely in registers) ----
        __builtin_amdgcn_s_setprio(1);
        #pragma unroll
        for (int d = 0; d < 4; ++d) {
            O[d] = mfma16(ap,  ldsb8(&Vt[cur][d * 16 + l15][h4 * 8]), O[d]);
            O[d] = mfma16(ap2, ldsb8(&Vt[cur][d * 16 + l15][32 + h4 * 8]), O[d]);
        }
        __builtin_amdgcn_s_setprio(0);

        __syncthreads();                   // one barrier per tile
    }

    // ---- epilogue: reduce l partials (once), normalize, store bf16 ----
    float lr = l_p;
    lr += __shfl_xor(lr, 16);
    lr += __shfl_xor(lr, 32);
    const float invl = 1.0f / lr;
    float inv[4];
    #pragma unroll
    for (int r2 = 0; r2 < 4; ++r2) inv[r2] = __shfl(invl, h4 * 4 + r2);
    u16* yp = yatt + ((size_t)(b * TT + q0 + w * 16 + h4 * 4)) * CC + h * DD + l15;
    #pragma unroll
    for (int r2 = 0; r2 < 4; ++r2)
        #pragma unroll
        for (int d = 0; d < 4; ++d)
            yp[(size_t)r2 * CC + d * 16] = f2b(O[d][r2] * inv[r2]);
}

// ---------------------------------------------------------------------------
extern "C" void kernel_launch(void* const* d_in, const int* in_sizes, int n_in,
                              void* d_out, int out_size, void* d_ws, size_t ws_size,
                              hipStream_t stream)
{
    (void)n_in; (void)out_size; (void)ws_size;

    const void* x      = d_in[0];
    const void* W_attn = d_in[1];
    const void* b_attn = d_in[2];
    const void* W_proj = d_in[3];
    const void* b_proj = d_in[4];

    // workspace layout (~30 MB)
    u16* qkv  = (u16*)d_ws;                       // [4096,2304] bf16
    u16* yatt = qkv + (size_t)MM * C3;            // [4096,768]  bf16
    u16* xb   = yatt;                             // bf16 x — lifetime disjoint
    u16* WaT  = yatt + (size_t)MM * CC;           // [2304,768]  bf16 (W_attn^T)
    u16* WpT  = WaT + (size_t)C3 * CC;            // [768,768]   bf16 (W_proj^T)
    u16* ba   = WpT + (size_t)CC * CC;            // [2304] bf16
    u16* bp   = ba + C3;                          // [768]  bf16
    int* flag = (int*)(bp + CC);                  // 1 int

    // host-side dtype inference from byte sizes; device detector as fallback
    int mode = -1;
    if (in_sizes[0] == MM * CC * 4) mode = 1;          // fp32 bytes
    else if (in_sizes[0] == MM * CC * 2) mode = 0;     // bf16 bytes
    if (mode < 0) {
        detect_kernel<<<1, 256, 0, stream>>>((const u16*)x, flag);
    }

    // fused prep: W transposes + x->bf16 (fp32 mode only) + biases
    fused_prep<<<2121, 256, 0, stream>>>(x, W_attn, b_attn, W_proj, b_proj,
                                         xb, WaT, WpT, ba, bp, flag, mode);

    // 1) qkv = x/xb @ W_attn + b_attn (bf16 out), 128x64 tiles, 1152 blocks
    gemm_mfma<4, 2><<<(MM / 128) * (C3 / 64), 256, 0, stream>>>(
        (const u16*)x, xb, WaT, ba, (void*)qkv, MM, C3, CC, flag, mode, 0);

    // 2) causal flash attention
    attn_mfma<<<dim3(TT / 64 * HH * BB, 1, 1), 256, 0, stream>>>(qkv, yatt);

    // 3) out = yatt @ W_proj + b_proj (out dtype follows mode), 64x64 tiles
    gemm_mfma<2, 2><<<(MM / 64) * (CC / 64), 256, 0, stream>>>(
        yatt, yatt, WpT, bp, d_out, MM, CC, CC, flag, mode, 1);
}